// Round 1
// baseline (3008.500 us; speedup 1.0000x reference)
//
#include <hip/hip_runtime.h>

#define D 128
#define EPS 1e-5f

// ---- scatter: agg[dst] += feat[src], cnt[dst] += 1 -------------------------
// 32 threads per edge, each handles 4 consecutive floats (float4 gather).
__global__ void scatter_kernel(const int* __restrict__ src, const int* __restrict__ dst,
                               const float* __restrict__ feat, float* __restrict__ agg,
                               float* __restrict__ cnt, int E, int do_cnt)
{
    int e = blockIdx.x * 8 + (threadIdx.x >> 5);
    int lane = threadIdx.x & 31;
    if (e >= E) return;
    int s = src[e];
    int d = dst[e];
    float4 v = ((const float4*)(feat + (size_t)s * D))[lane];
    float* base = agg + (size_t)d * D + lane * 4;
    unsafeAtomicAdd(base + 0, v.x);
    unsafeAtomicAdd(base + 1, v.y);
    unsafeAtomicAdd(base + 2, v.z);
    unsafeAtomicAdd(base + 3, v.w);
    if (do_cnt && lane == 0) unsafeAtomicAdd(cnt + d, 1.0f);
}

// ---- cnt -> 1/max(cnt,1) in place ------------------------------------------
__global__ void inv_kernel(float* __restrict__ cnt, int n)
{
    int i = blockIdx.x * 256 + threadIdx.x;
    if (i < n) cnt[i] = 1.0f / fmaxf(cnt[i], 1.0f);
}

// ---- build wT[256][128]: k<128 -> wl[j][k], k>=128 -> wr[j][k-128] ---------
__global__ void wt_kernel(const float* __restrict__ wl, const float* __restrict__ wr,
                          float* __restrict__ wT)
{
    int idx = blockIdx.x * 256 + threadIdx.x;   // 0..32767
    int k = idx >> 7, j = idx & 127;
    wT[idx] = (k < D) ? wl[j * D + k] : wr[j * D + (k - D)];
}

// ---- fused conv: out[n][j] = bias[j] + inv[n]*(part1[n]·wl[j]) + part2[n]·wr[j]
// 32 nodes per block; thread computes 4 nodes x 4 features.
__global__ __launch_bounds__(256) void conv_kernel(
    const float* __restrict__ part1, const float* __restrict__ inv,
    const float* __restrict__ part2, const float* __restrict__ wT,
    const float* __restrict__ bias, float* __restrict__ out, int n_nodes)
{
    __shared__ float a[32][256];
    int nb = blockIdx.x * 32;
    // stage A tile: [mean_row | part2_row], 32 nodes x 256
    for (int q = threadIdx.x; q < 2048; q += 256) {
        int m = q >> 6;          // node in tile
        int kq = q & 63;         // float4 index within 256-wide row
        int node = nb + m;
        float4 v = make_float4(0.f, 0.f, 0.f, 0.f);
        if (node < n_nodes) {
            if (kq < 32) {
                v = ((const float4*)(part1 + (size_t)node * D))[kq];
                float s = inv[node];
                v.x *= s; v.y *= s; v.z *= s; v.w *= s;
            } else {
                v = ((const float4*)(part2 + (size_t)node * D))[kq - 32];
            }
        }
        ((float4*)&a[m][0])[kq] = v;
    }
    __syncthreads();

    int j4 = (threadIdx.x & 31) * 4;
    int mBase = threadIdx.x >> 5;
    float b0 = bias[j4], b1 = bias[j4 + 1], b2 = bias[j4 + 2], b3 = bias[j4 + 3];
    float acc[4][4];
#pragma unroll
    for (int i = 0; i < 4; i++) { acc[i][0] = b0; acc[i][1] = b1; acc[i][2] = b2; acc[i][3] = b3; }

    for (int k = 0; k < 256; k += 4) {
        float4 w0 = *(const float4*)&wT[(k + 0) * D + j4];
        float4 w1 = *(const float4*)&wT[(k + 1) * D + j4];
        float4 w2 = *(const float4*)&wT[(k + 2) * D + j4];
        float4 w3 = *(const float4*)&wT[(k + 3) * D + j4];
#pragma unroll
        for (int i = 0; i < 4; i++) {
            float4 av = *(const float4*)&a[mBase + i * 8][k];
            acc[i][0] += av.x * w0.x + av.y * w1.x + av.z * w2.x + av.w * w3.x;
            acc[i][1] += av.x * w0.y + av.y * w1.y + av.z * w2.y + av.w * w3.y;
            acc[i][2] += av.x * w0.z + av.y * w1.z + av.z * w2.z + av.w * w3.z;
            acc[i][3] += av.x * w0.w + av.y * w1.w + av.z * w2.w + av.w * w3.w;
        }
    }
#pragma unroll
    for (int i = 0; i < 4; i++) {
        int node = nb + mBase + i * 8;
        if (node < n_nodes) {
            float4 o = make_float4(acc[i][0], acc[i][1], acc[i][2], acc[i][3]);
            ((float4*)(out + (size_t)node * D))[j4 >> 2] = o;
        }
    }
}

// ---- per-feature column sum / sumsq ----------------------------------------
__global__ void stats_kernel(const float* __restrict__ h, float* __restrict__ stats, int n)
{
    int j = threadIdx.x & 127;
    int half = threadIdx.x >> 7;
    float s = 0.f, ss = 0.f;
    for (int r = blockIdx.x * 2 + half; r < n; r += gridDim.x * 2) {
        float v = h[(size_t)r * D + j];
        s += v;
        ss += v * v;
    }
    __shared__ float buf[512];
    buf[threadIdx.x] = s;
    buf[256 + threadIdx.x] = ss;
    __syncthreads();
    if (threadIdx.x < 128) {
        s = buf[threadIdx.x] + buf[threadIdx.x + 128];
        ss = buf[256 + threadIdx.x] + buf[256 + threadIdx.x + 128];
        unsafeAtomicAdd(&stats[j], s);
        unsafeAtomicAdd(&stats[128 + j], ss);
    }
}

// ---- BN scale/shift from stats ---------------------------------------------
__global__ void bnfin_kernel(const float* __restrict__ stats, const float* __restrict__ gamma,
                             const float* __restrict__ beta, float* __restrict__ scsh, float n_inv)
{
    int j = threadIdx.x;
    float mean = stats[j] * n_inv;
    float var = fmaxf(stats[128 + j] * n_inv - mean * mean, 0.f);
    float sc = gamma[j] * rsqrtf(var + EPS);
    scsh[j] = sc;
    scsh[128 + j] = beta[j] - mean * sc;
}

// ---- h = relu(h*scale + shift), in place, float4 ---------------------------
__global__ void bnapply_kernel(float* __restrict__ h, const float* __restrict__ scsh, int total4)
{
    int idx = blockIdx.x * 256 + threadIdx.x;
    if (idx >= total4) return;
    int jq = idx & 31;
    float4 v = ((float4*)h)[idx];
    float4 sc = ((const float4*)scsh)[jq];
    float4 sh = ((const float4*)(scsh + 128))[jq];
    v.x = fmaxf(v.x * sc.x + sh.x, 0.f);
    v.y = fmaxf(v.y * sc.y + sh.y, 0.f);
    v.z = fmaxf(v.z * sc.z + sh.z, 0.f);
    v.w = fmaxf(v.w * sc.w + sh.w, 0.f);
    ((float4*)h)[idx] = v;
}

extern "C" void kernel_launch(void* const* d_in, const int* in_sizes, int n_in,
                              void* d_out, int out_size, void* d_ws, size_t ws_size,
                              hipStream_t stream)
{
    const float* x     = (const float*)d_in[0];
    const int*   ei    = (const int*)d_in[1];
    const float* w1_l  = (const float*)d_in[2];
    const float* b1_l  = (const float*)d_in[3];
    const float* w1_r  = (const float*)d_in[4];
    const float* w2_l  = (const float*)d_in[5];
    const float* b2_l  = (const float*)d_in[6];
    const float* w2_r  = (const float*)d_in[7];
    const float* gamma = (const float*)d_in[8];
    const float* beta  = (const float*)d_in[9];

    int N = in_sizes[0] / D;
    int E = in_sizes[1] / 2;
    const int* src = ei;
    const int* dst = ei + E;

    // workspace layout (floats): agg[N*D] | h[N*D] | cnt[N] | stats[256] | scsh[256] | wT1[32768] | wT2[32768]
    float* ws    = (float*)d_ws;
    float* agg   = ws;
    float* h     = agg + (size_t)N * D;
    float* cnt   = h + (size_t)N * D;
    float* stats = cnt + N;
    float* scsh  = stats + 256;
    float* wT1   = scsh + 256;
    float* wT2   = wT1 + 32768;

    hipMemsetAsync(agg, 0, (size_t)N * D * sizeof(float), stream);
    hipMemsetAsync(cnt, 0, (size_t)(N + 256) * sizeof(float), stream);

    wt_kernel<<<128, 256, 0, stream>>>(w1_l, w1_r, wT1);
    wt_kernel<<<128, 256, 0, stream>>>(w2_l, w2_r, wT2);

    int sblocks = (E + 7) / 8;
    int cblocks = (N + 31) / 32;

    // layer 1
    scatter_kernel<<<sblocks, 256, 0, stream>>>(src, dst, x, agg, cnt, E, 1);
    inv_kernel<<<(N + 255) / 256, 256, 0, stream>>>(cnt, N);
    conv_kernel<<<cblocks, 256, 0, stream>>>(agg, cnt, x, wT1, b1_l, h, N);

    // batch norm + relu
    stats_kernel<<<256, 256, 0, stream>>>(h, stats, N);
    bnfin_kernel<<<1, 128, 0, stream>>>(stats, gamma, beta, scsh, 1.0f / (float)N);
    bnapply_kernel<<<(N * 32 + 255) / 256, 256, 0, stream>>>(h, scsh, N * 32);

    // layer 2
    hipMemsetAsync(agg, 0, (size_t)N * D * sizeof(float), stream);
    scatter_kernel<<<sblocks, 256, 0, stream>>>(src, dst, h, agg, cnt, E, 0);
    conv_kernel<<<cblocks, 256, 0, stream>>>(agg, cnt, h, wT2, b2_l, (float*)d_out, N);
}

// Round 2
// 623.777 us; speedup vs baseline: 4.8230x; 4.8230x over previous
//
#include <hip/hip_runtime.h>

#define D 128
#define EPS 1e-5f

// ---- CSR build: degree histogram -------------------------------------------
__global__ void hist_kernel(const int* __restrict__ dst, int* __restrict__ deg, int E)
{
    int e = blockIdx.x * 256 + threadIdx.x;
    if (e < E) atomicAdd(&deg[dst[e]], 1);
}

// ---- CSR build: exclusive scan of deg -> rowptr (and cursor copy) ----------
__global__ __launch_bounds__(1024) void scan_kernel(const int* __restrict__ deg,
                                                    int* __restrict__ rowptr,
                                                    int* __restrict__ cursor, int n)
{
    __shared__ int sums[1024];
    int t = threadIdx.x;
    int chunk = (n + 1023) / 1024;
    int begin = t * chunk;
    int end = min(begin + chunk, n);
    int s = 0;
    for (int i = begin; i < end; i++) s += deg[i];
    sums[t] = s;
    __syncthreads();
    for (int off = 1; off < 1024; off <<= 1) {
        int v = (t >= off) ? sums[t - off] : 0;
        __syncthreads();
        sums[t] += v;
        __syncthreads();
    }
    int base = (t == 0) ? 0 : sums[t - 1];
    for (int i = begin; i < end; i++) {
        rowptr[i] = base;
        cursor[i] = base;
        base += deg[i];
    }
    if (t == 0) rowptr[n] = sums[1023];
}

// ---- CSR build: bucket edges by dst ----------------------------------------
__global__ void fill_kernel(const int* __restrict__ src, const int* __restrict__ dst,
                            int* __restrict__ cursor, int* __restrict__ col, int E)
{
    int e = blockIdx.x * 256 + threadIdx.x;
    if (e < E) {
        int p = atomicAdd(&cursor[dst[e]], 1);
        col[p] = src[e];
    }
}

// ---- gather aggregation: agg[n] = mean of feat[col[rowptr[n]..rowptr[n+1])] -
// one wave (64 lanes) per node, float2 per lane = 512 B/row coalesced
__global__ __launch_bounds__(256) void agg_kernel(const int* __restrict__ rowptr,
                                                  const int* __restrict__ col,
                                                  const float* __restrict__ feat,
                                                  float* __restrict__ agg, int n)
{
    int node = blockIdx.x * 4 + (threadIdx.x >> 6);
    if (node >= n) return;
    int lane = threadIdx.x & 63;
    int r0 = rowptr[node], r1 = rowptr[node + 1];
    const float2* f2 = (const float2*)feat;
    float sx = 0.f, sy = 0.f;
    for (int i = r0; i < r1; i++) {
        int c = col[i];
        float2 v = f2[(size_t)c * 64 + lane];
        sx += v.x; sy += v.y;
    }
    float sc = 1.0f / fmaxf((float)(r1 - r0), 1.0f);
    ((float2*)(agg + (size_t)node * D))[lane] = make_float2(sx * sc, sy * sc);
}

// ---- build wT[256][128]: k<128 -> wl[j][k], k>=128 -> wr[j][k-128] ---------
__global__ void wt_kernel(const float* __restrict__ wl, const float* __restrict__ wr,
                          float* __restrict__ wT)
{
    int idx = blockIdx.x * 256 + threadIdx.x;   // 0..32767
    int k = idx >> 7, j = idx & 127;
    wT[idx] = (k < D) ? wl[j * D + k] : wr[j * D + (k - D)];
}

// ---- fused conv: out[n][j] = bias[j] + part1[n]·wl[j] + part2[n]·wr[j] -----
// 32 nodes per block; thread computes 4 nodes x 4 features.
// Safe for out == part2 (each block reads only its own 32 rows into LDS
// before writing those same rows).
__global__ __launch_bounds__(256) void conv_kernel(
    const float* __restrict__ part1, const float* __restrict__ part2,
    const float* __restrict__ wT, const float* __restrict__ bias,
    float* __restrict__ out, int n_nodes)
{
    __shared__ float a[32][256];
    int nb = blockIdx.x * 32;
    for (int q = threadIdx.x; q < 2048; q += 256) {
        int m = q >> 6;          // node in tile
        int kq = q & 63;         // float4 index within 256-wide row
        int node = nb + m;
        float4 v = make_float4(0.f, 0.f, 0.f, 0.f);
        if (node < n_nodes) {
            v = (kq < 32) ? ((const float4*)(part1 + (size_t)node * D))[kq]
                          : ((const float4*)(part2 + (size_t)node * D))[kq - 32];
        }
        ((float4*)&a[m][0])[kq] = v;
    }
    __syncthreads();

    int j4 = (threadIdx.x & 31) * 4;
    int mBase = threadIdx.x >> 5;
    float b0 = bias[j4], b1 = bias[j4 + 1], b2 = bias[j4 + 2], b3 = bias[j4 + 3];
    float acc[4][4];
#pragma unroll
    for (int i = 0; i < 4; i++) { acc[i][0] = b0; acc[i][1] = b1; acc[i][2] = b2; acc[i][3] = b3; }

    for (int k = 0; k < 256; k += 4) {
        float4 w0 = *(const float4*)&wT[(k + 0) * D + j4];
        float4 w1 = *(const float4*)&wT[(k + 1) * D + j4];
        float4 w2 = *(const float4*)&wT[(k + 2) * D + j4];
        float4 w3 = *(const float4*)&wT[(k + 3) * D + j4];
#pragma unroll
        for (int i = 0; i < 4; i++) {
            float4 av = *(const float4*)&a[mBase + i * 8][k];
            acc[i][0] += av.x * w0.x + av.y * w1.x + av.z * w2.x + av.w * w3.x;
            acc[i][1] += av.x * w0.y + av.y * w1.y + av.z * w2.y + av.w * w3.y;
            acc[i][2] += av.x * w0.z + av.y * w1.z + av.z * w2.z + av.w * w3.z;
            acc[i][3] += av.x * w0.w + av.y * w1.w + av.z * w2.w + av.w * w3.w;
        }
    }
#pragma unroll
    for (int i = 0; i < 4; i++) {
        int node = nb + mBase + i * 8;
        if (node < n_nodes) {
            float4 o = make_float4(acc[i][0], acc[i][1], acc[i][2], acc[i][3]);
            ((float4*)(out + (size_t)node * D))[j4 >> 2] = o;
        }
    }
}

// ---- per-feature column sum / sumsq ----------------------------------------
__global__ void stats_kernel(const float* __restrict__ h, float* __restrict__ stats, int n)
{
    int j = threadIdx.x & 127;
    int half = threadIdx.x >> 7;
    float s = 0.f, ss = 0.f;
    for (int r = blockIdx.x * 2 + half; r < n; r += gridDim.x * 2) {
        float v = h[(size_t)r * D + j];
        s += v;
        ss += v * v;
    }
    __shared__ float buf[512];
    buf[threadIdx.x] = s;
    buf[256 + threadIdx.x] = ss;
    __syncthreads();
    if (threadIdx.x < 128) {
        s = buf[threadIdx.x] + buf[threadIdx.x + 128];
        ss = buf[256 + threadIdx.x] + buf[256 + threadIdx.x + 128];
        unsafeAtomicAdd(&stats[j], s);
        unsafeAtomicAdd(&stats[128 + j], ss);
    }
}

// ---- BN scale/shift from stats ---------------------------------------------
__global__ void bnfin_kernel(const float* __restrict__ stats, const float* __restrict__ gamma,
                             const float* __restrict__ beta, float* __restrict__ scsh, float n_inv)
{
    int j = threadIdx.x;
    float mean = stats[j] * n_inv;
    float var = fmaxf(stats[128 + j] * n_inv - mean * mean, 0.f);
    float sc = gamma[j] * rsqrtf(var + EPS);
    scsh[j] = sc;
    scsh[128 + j] = beta[j] - mean * sc;
}

// ---- h = relu(h*scale + shift), in place, float4 ---------------------------
__global__ void bnapply_kernel(float* __restrict__ h, const float* __restrict__ scsh, int total4)
{
    int idx = blockIdx.x * 256 + threadIdx.x;
    if (idx >= total4) return;
    int jq = idx & 31;
    float4 v = ((float4*)h)[idx];
    float4 sc = ((const float4*)scsh)[jq];
    float4 sh = ((const float4*)(scsh + 128))[jq];
    v.x = fmaxf(v.x * sc.x + sh.x, 0.f);
    v.y = fmaxf(v.y * sc.y + sh.y, 0.f);
    v.z = fmaxf(v.z * sc.z + sh.z, 0.f);
    v.w = fmaxf(v.w * sc.w + sh.w, 0.f);
    ((float4*)h)[idx] = v;
}

extern "C" void kernel_launch(void* const* d_in, const int* in_sizes, int n_in,
                              void* d_out, int out_size, void* d_ws, size_t ws_size,
                              hipStream_t stream)
{
    const float* x     = (const float*)d_in[0];
    const int*   ei    = (const int*)d_in[1];
    const float* w1_l  = (const float*)d_in[2];
    const float* b1_l  = (const float*)d_in[3];
    const float* w1_r  = (const float*)d_in[4];
    const float* w2_l  = (const float*)d_in[5];
    const float* b2_l  = (const float*)d_in[6];
    const float* w2_r  = (const float*)d_in[7];
    const float* gamma = (const float*)d_in[8];
    const float* beta  = (const float*)d_in[9];

    int N = in_sizes[0] / D;
    int E = in_sizes[1] / 2;
    const int* src = ei;
    const int* dst = ei + E;

    // workspace layout:
    // floats: agg[N*D] | stats[256] | scsh[256] | wT1[32768] | wT2[32768]
    // ints:   deg[N] | rowptr[N+1] | cursor[N] | col[E]
    float* ws     = (float*)d_ws;
    float* agg    = ws;
    float* stats  = agg + (size_t)N * D;
    float* scsh   = stats + 256;
    float* wT1    = scsh + 256;
    float* wT2    = wT1 + 32768;
    int*   deg    = (int*)(wT2 + 32768);
    int*   rowptr = deg + N;
    int*   cursor = rowptr + N + 1;
    int*   col    = cursor + N;

    float* h = (float*)d_out;   // use d_out as the hidden buffer (fully rewritten)

    hipMemsetAsync(deg, 0, (size_t)N * sizeof(int), stream);
    hipMemsetAsync(stats, 0, 256 * sizeof(float), stream);

    wt_kernel<<<128, 256, 0, stream>>>(w1_l, w1_r, wT1);
    wt_kernel<<<128, 256, 0, stream>>>(w2_l, w2_r, wT2);

    int eblocks = (E + 255) / 256;
    int ablocks = (N + 3) / 4;
    int cblocks = (N + 31) / 32;

    // CSR build (shared by both layers)
    hist_kernel<<<eblocks, 256, 0, stream>>>(dst, deg, E);
    scan_kernel<<<1, 1024, 0, stream>>>(deg, rowptr, cursor, N);
    fill_kernel<<<eblocks, 256, 0, stream>>>(src, dst, cursor, col, E);

    // layer 1
    agg_kernel<<<ablocks, 256, 0, stream>>>(rowptr, col, x, agg, N);
    conv_kernel<<<cblocks, 256, 0, stream>>>(agg, x, wT1, b1_l, h, N);

    // batch norm + relu (in place on h)
    stats_kernel<<<256, 256, 0, stream>>>(h, stats, N);
    bnfin_kernel<<<1, 128, 0, stream>>>(stats, gamma, beta, scsh, 1.0f / (float)N);
    bnapply_kernel<<<(N * 32 + 255) / 256, 256, 0, stream>>>(h, scsh, N * 32);

    // layer 2
    agg_kernel<<<ablocks, 256, 0, stream>>>(rowptr, col, h, agg, N);
    conv_kernel<<<cblocks, 256, 0, stream>>>(agg, h, wT2, b2_l, (float*)d_out, N);
}

// Round 3
// 527.811 us; speedup vs baseline: 5.7000x; 1.1818x over previous
//
#include <hip/hip_runtime.h>

#define D 128
#define EPS 1e-5f
#define SCAN_CHUNK 2048

// ---- CSR build: degree histogram -------------------------------------------
__global__ void hist_kernel(const int* __restrict__ dst, int* __restrict__ deg, int E)
{
    int e = blockIdx.x * 256 + threadIdx.x;
    if (e < E) atomicAdd(&deg[dst[e]], 1);
}

// ---- scan phase A: per-block (2048-chunk) sums ------------------------------
__global__ __launch_bounds__(256) void scanA_kernel(const int* __restrict__ deg,
                                                    int* __restrict__ bsum, int n)
{
    __shared__ int red[256];
    int base = blockIdx.x * SCAN_CHUNK;
    int s = 0;
    for (int i = threadIdx.x; i < SCAN_CHUNK; i += 256) {
        int idx = base + i;
        if (idx < n) s += deg[idx];
    }
    red[threadIdx.x] = s;
    __syncthreads();
    for (int off = 128; off > 0; off >>= 1) {
        if (threadIdx.x < off) red[threadIdx.x] += red[threadIdx.x + off];
        __syncthreads();
    }
    if (threadIdx.x == 0) bsum[blockIdx.x] = red[0];
}

// ---- scan phase B: one wave, exclusive scan of block sums (nb <= 64) -------
__global__ void scanB_kernel(int* __restrict__ bsum, int nb)
{
    int t = threadIdx.x;
    int v = (t < nb) ? bsum[t] : 0;
    for (int off = 1; off < 64; off <<= 1) {
        int u = __shfl_up(v, off);
        if (t >= off) v += u;
    }
    int ex = __shfl_up(v, 1);
    if (t == 0) ex = 0;
    if (t < nb) bsum[t] = ex;
}

// ---- scan phase C: local exclusive scan + block offset -> rowptr, cursor ---
__global__ __launch_bounds__(256) void scanC_kernel(const int* __restrict__ deg,
                                                    const int* __restrict__ bsum,
                                                    int* __restrict__ rowptr,
                                                    int* __restrict__ cursor, int n, int E)
{
    __shared__ int tsum[256];
    int t = threadIdx.x;
    int tb = blockIdx.x * SCAN_CHUNK + t * 8;
    int v[8];
    int s = 0;
#pragma unroll
    for (int k = 0; k < 8; k++) {
        int idx = tb + k;
        v[k] = (idx < n) ? deg[idx] : 0;
        s += v[k];
    }
    tsum[t] = s;
    __syncthreads();
    // inclusive Hillis-Steele scan over the 256 thread sums
    for (int off = 1; off < 256; off <<= 1) {
        int u = (t >= off) ? tsum[t - off] : 0;
        __syncthreads();
        tsum[t] += u;
        __syncthreads();
    }
    int run = bsum[blockIdx.x] + tsum[t] - s;   // exclusive prefix for this thread
#pragma unroll
    for (int k = 0; k < 8; k++) {
        int idx = tb + k;
        if (idx < n) { rowptr[idx] = run; cursor[idx] = run; run += v[k]; }
    }
    if (blockIdx.x == 0 && t == 0) rowptr[n] = E;  // total degree == E by construction
}

// ---- CSR build: bucket edges by dst ----------------------------------------
__global__ void fill_kernel(const int* __restrict__ src, const int* __restrict__ dst,
                            int* __restrict__ cursor, int* __restrict__ col, int E)
{
    int e = blockIdx.x * 256 + threadIdx.x;
    if (e < E) {
        int p = atomicAdd(&cursor[dst[e]], 1);
        col[p] = src[e];
    }
}

// ---- gather aggregation: agg[n] = mean of feat[col[rowptr[n]..rowptr[n+1])] -
__global__ __launch_bounds__(256) void agg_kernel(const int* __restrict__ rowptr,
                                                  const int* __restrict__ col,
                                                  const float* __restrict__ feat,
                                                  float* __restrict__ agg, int n)
{
    int node = blockIdx.x * 4 + (threadIdx.x >> 6);
    if (node >= n) return;
    int lane = threadIdx.x & 63;
    int r0 = rowptr[node], r1 = rowptr[node + 1];
    const float2* f2 = (const float2*)feat;
    float sx = 0.f, sy = 0.f;
    for (int i = r0; i < r1; i++) {
        int c = col[i];
        float2 v = f2[(size_t)c * 64 + lane];
        sx += v.x; sy += v.y;
    }
    float sc = 1.0f / fmaxf((float)(r1 - r0), 1.0f);
    ((float2*)(agg + (size_t)node * D))[lane] = make_float2(sx * sc, sy * sc);
}

// ---- build wT1/wT2 [256][128] in one launch --------------------------------
__global__ void wt_kernel(const float* __restrict__ w1l, const float* __restrict__ w1r,
                          const float* __restrict__ w2l, const float* __restrict__ w2r,
                          float* __restrict__ wT1, float* __restrict__ wT2)
{
    int idx = blockIdx.x * 256 + threadIdx.x;   // 0..65535
    int which = idx >> 15;
    int rem = idx & 32767;
    int k = rem >> 7, j = rem & 127;
    const float* wl = which ? w2l : w1l;
    const float* wr = which ? w2r : w1r;
    float* wT = which ? wT2 : wT1;
    wT[rem] = (k < D) ? wl[j * D + k] : wr[j * D + (k - D)];
}

// ---- fused conv: out[n][j] = bias[j] + part1[n]·wl[j] + part2[n]·wr[j] -----
__global__ __launch_bounds__(256) void conv_kernel(
    const float* __restrict__ part1, const float* __restrict__ part2,
    const float* __restrict__ wT, const float* __restrict__ bias,
    float* __restrict__ out, int n_nodes)
{
    __shared__ float a[32][256];
    int nb = blockIdx.x * 32;
    for (int q = threadIdx.x; q < 2048; q += 256) {
        int m = q >> 6;
        int kq = q & 63;
        int node = nb + m;
        float4 v = make_float4(0.f, 0.f, 0.f, 0.f);
        if (node < n_nodes) {
            v = (kq < 32) ? ((const float4*)(part1 + (size_t)node * D))[kq]
                          : ((const float4*)(part2 + (size_t)node * D))[kq - 32];
        }
        ((float4*)&a[m][0])[kq] = v;
    }
    __syncthreads();

    int j4 = (threadIdx.x & 31) * 4;
    int mBase = threadIdx.x >> 5;
    float b0 = bias[j4], b1 = bias[j4 + 1], b2 = bias[j4 + 2], b3 = bias[j4 + 3];
    float acc[4][4];
#pragma unroll
    for (int i = 0; i < 4; i++) { acc[i][0] = b0; acc[i][1] = b1; acc[i][2] = b2; acc[i][3] = b3; }

    for (int k = 0; k < 256; k += 4) {
        float4 w0 = *(const float4*)&wT[(k + 0) * D + j4];
        float4 w1 = *(const float4*)&wT[(k + 1) * D + j4];
        float4 w2 = *(const float4*)&wT[(k + 2) * D + j4];
        float4 w3 = *(const float4*)&wT[(k + 3) * D + j4];
#pragma unroll
        for (int i = 0; i < 4; i++) {
            float4 av = *(const float4*)&a[mBase + i * 8][k];
            acc[i][0] += av.x * w0.x + av.y * w1.x + av.z * w2.x + av.w * w3.x;
            acc[i][1] += av.x * w0.y + av.y * w1.y + av.z * w2.y + av.w * w3.y;
            acc[i][2] += av.x * w0.z + av.y * w1.z + av.z * w2.z + av.w * w3.z;
            acc[i][3] += av.x * w0.w + av.y * w1.w + av.z * w2.w + av.w * w3.w;
        }
    }
#pragma unroll
    for (int i = 0; i < 4; i++) {
        int node = nb + mBase + i * 8;
        if (node < n_nodes) {
            float4 o = make_float4(acc[i][0], acc[i][1], acc[i][2], acc[i][3]);
            ((float4*)(out + (size_t)node * D))[j4 >> 2] = o;
        }
    }
}

// ---- per-feature column sum / sumsq ----------------------------------------
__global__ void stats_kernel(const float* __restrict__ h, float* __restrict__ stats, int n)
{
    int j = threadIdx.x & 127;
    int half = threadIdx.x >> 7;
    float s = 0.f, ss = 0.f;
    for (int r = blockIdx.x * 2 + half; r < n; r += gridDim.x * 2) {
        float v = h[(size_t)r * D + j];
        s += v;
        ss += v * v;
    }
    __shared__ float buf[512];
    buf[threadIdx.x] = s;
    buf[256 + threadIdx.x] = ss;
    __syncthreads();
    if (threadIdx.x < 128) {
        s = buf[threadIdx.x] + buf[threadIdx.x + 128];
        ss = buf[256 + threadIdx.x] + buf[256 + threadIdx.x + 128];
        unsafeAtomicAdd(&stats[j], s);
        unsafeAtomicAdd(&stats[128 + j], ss);
    }
}

// ---- BN scale/shift from stats ---------------------------------------------
__global__ void bnfin_kernel(const float* __restrict__ stats, const float* __restrict__ gamma,
                             const float* __restrict__ beta, float* __restrict__ scsh, float n_inv)
{
    int j = threadIdx.x;
    float mean = stats[j] * n_inv;
    float var = fmaxf(stats[128 + j] * n_inv - mean * mean, 0.f);
    float sc = gamma[j] * rsqrtf(var + EPS);
    scsh[j] = sc;
    scsh[128 + j] = beta[j] - mean * sc;
}

// ---- h = relu(h*scale + shift), in place, float4 ---------------------------
__global__ void bnapply_kernel(float* __restrict__ h, const float* __restrict__ scsh, int total4)
{
    int idx = blockIdx.x * 256 + threadIdx.x;
    if (idx >= total4) return;
    int jq = idx & 31;
    float4 v = ((float4*)h)[idx];
    float4 sc = ((const float4*)scsh)[jq];
    float4 sh = ((const float4*)(scsh + 128))[jq];
    v.x = fmaxf(v.x * sc.x + sh.x, 0.f);
    v.y = fmaxf(v.y * sc.y + sh.y, 0.f);
    v.z = fmaxf(v.z * sc.z + sh.z, 0.f);
    v.w = fmaxf(v.w * sc.w + sh.w, 0.f);
    ((float4*)h)[idx] = v;
}

extern "C" void kernel_launch(void* const* d_in, const int* in_sizes, int n_in,
                              void* d_out, int out_size, void* d_ws, size_t ws_size,
                              hipStream_t stream)
{
    const float* x     = (const float*)d_in[0];
    const int*   ei    = (const int*)d_in[1];
    const float* w1_l  = (const float*)d_in[2];
    const float* b1_l  = (const float*)d_in[3];
    const float* w1_r  = (const float*)d_in[4];
    const float* w2_l  = (const float*)d_in[5];
    const float* b2_l  = (const float*)d_in[6];
    const float* w2_r  = (const float*)d_in[7];
    const float* gamma = (const float*)d_in[8];
    const float* beta  = (const float*)d_in[9];

    int N = in_sizes[0] / D;
    int E = in_sizes[1] / 2;
    const int* src = ei;
    const int* dst = ei + E;

    // workspace layout:
    // floats: agg[N*D] | stats[256] | scsh[256] | wT1[32768] | wT2[32768]
    // ints:   deg[N] | rowptr[N+1] | cursor[N] | col[E] | bsum[64]
    float* ws     = (float*)d_ws;
    float* agg    = ws;
    float* stats  = agg + (size_t)N * D;
    float* scsh   = stats + 256;
    float* wT1    = scsh + 256;
    float* wT2    = wT1 + 32768;
    int*   deg    = (int*)(wT2 + 32768);
    int*   rowptr = deg + N;
    int*   cursor = rowptr + N + 1;
    int*   col    = cursor + N;
    int*   bsum   = col + E;

    float* h = (float*)d_out;   // hidden buffer lives in d_out (fully rewritten by layer 2)

    hipMemsetAsync(deg, 0, (size_t)N * sizeof(int), stream);
    hipMemsetAsync(stats, 0, 256 * sizeof(float), stream);

    wt_kernel<<<256, 256, 0, stream>>>(w1_l, w1_r, w2_l, w2_r, wT1, wT2);

    int eblocks = (E + 255) / 256;
    int ablocks = (N + 3) / 4;
    int cblocks = (N + 31) / 32;
    int nscan   = (N + SCAN_CHUNK - 1) / SCAN_CHUNK;   // 25 for N=50000

    // CSR build (shared by both layers)
    hist_kernel<<<eblocks, 256, 0, stream>>>(dst, deg, E);
    scanA_kernel<<<nscan, 256, 0, stream>>>(deg, bsum, N);
    scanB_kernel<<<1, 64, 0, stream>>>(bsum, nscan);
    scanC_kernel<<<nscan, 256, 0, stream>>>(deg, bsum, rowptr, cursor, N, E);
    fill_kernel<<<eblocks, 256, 0, stream>>>(src, dst, cursor, col, E);

    // layer 1
    agg_kernel<<<ablocks, 256, 0, stream>>>(rowptr, col, x, agg, N);
    conv_kernel<<<cblocks, 256, 0, stream>>>(agg, x, wT1, b1_l, h, N);

    // batch norm + relu (in place on h)
    stats_kernel<<<256, 256, 0, stream>>>(h, stats, N);
    bnfin_kernel<<<1, 128, 0, stream>>>(stats, gamma, beta, scsh, 1.0f / (float)N);
    bnapply_kernel<<<(N * 32 + 255) / 256, 256, 0, stream>>>(h, scsh, N * 32);

    // layer 2
    agg_kernel<<<ablocks, 256, 0, stream>>>(rowptr, col, h, agg, N);
    conv_kernel<<<cblocks, 256, 0, stream>>>(agg, h, wT2, b2_l, (float*)d_out, N);
}

// Round 4
// 433.189 us; speedup vs baseline: 6.9450x; 1.2184x over previous
//
#include <hip/hip_runtime.h>

#define D 128
#define EPS 1e-5f
#define SCAN_CHUNK 2048

typedef unsigned int uint;

// ---- bf16 pack/unpack helpers (RTNE) ---------------------------------------
__device__ __forceinline__ uint pack_bf16(float a, float b)
{
    uint ua = __float_as_uint(a);
    uint ub = __float_as_uint(b);
    ua += 0x7FFFu + ((ua >> 16) & 1u);
    ub += 0x7FFFu + ((ub >> 16) & 1u);
    return (ua >> 16) | (ub & 0xFFFF0000u);
}
__device__ __forceinline__ float bf_lo(uint v) { return __uint_as_float(v << 16); }
__device__ __forceinline__ float bf_hi(uint v) { return __uint_as_float(v & 0xFFFF0000u); }

// ---- prep: x -> xb (bf16 packed) AND build wT1/wT2 [256][128] ---------------
__global__ void prep_kernel(const float* __restrict__ x, uint* __restrict__ xb, int ncvt,
                            const float* __restrict__ w1l, const float* __restrict__ w1r,
                            const float* __restrict__ w2l, const float* __restrict__ w2r,
                            float* __restrict__ wT1, float* __restrict__ wT2)
{
    int idx = blockIdx.x * 256 + threadIdx.x;
    if (idx < ncvt) {
        float4 v = ((const float4*)x)[idx];
        uint2 o;
        o.x = pack_bf16(v.x, v.y);
        o.y = pack_bf16(v.z, v.w);
        ((uint2*)xb)[idx] = o;
    } else {
        int r = idx - ncvt;
        if (r < 65536) {
            int which = r >> 15;
            int rem = r & 32767;
            int k = rem >> 7, j = rem & 127;
            const float* wl = which ? w2l : w1l;
            const float* wr = which ? w2r : w1r;
            float* wT = which ? wT2 : wT1;
            wT[rem] = (k < D) ? wl[j * D + k] : wr[j * D + (k - D)];
        }
    }
}

// ---- CSR build: degree histogram -------------------------------------------
__global__ void hist_kernel(const int* __restrict__ dst, int* __restrict__ deg, int E)
{
    int e = blockIdx.x * 256 + threadIdx.x;
    if (e < E) atomicAdd(&deg[dst[e]], 1);
}

// ---- scan phase A: per-block (2048-chunk) sums ------------------------------
__global__ __launch_bounds__(256) void scanA_kernel(const int* __restrict__ deg,
                                                    int* __restrict__ bsum, int n)
{
    __shared__ int red[256];
    int base = blockIdx.x * SCAN_CHUNK;
    int s = 0;
    for (int i = threadIdx.x; i < SCAN_CHUNK; i += 256) {
        int idx = base + i;
        if (idx < n) s += deg[idx];
    }
    red[threadIdx.x] = s;
    __syncthreads();
    for (int off = 128; off > 0; off >>= 1) {
        if (threadIdx.x < off) red[threadIdx.x] += red[threadIdx.x + off];
        __syncthreads();
    }
    if (threadIdx.x == 0) bsum[blockIdx.x] = red[0];
}

// ---- scan phase B: one wave, exclusive scan of block sums (nb <= 64) -------
__global__ void scanB_kernel(int* __restrict__ bsum, int nb)
{
    int t = threadIdx.x;
    int v = (t < nb) ? bsum[t] : 0;
    for (int off = 1; off < 64; off <<= 1) {
        int u = __shfl_up(v, off);
        if (t >= off) v += u;
    }
    int ex = __shfl_up(v, 1);
    if (t == 0) ex = 0;
    if (t < nb) bsum[t] = ex;
}

// ---- scan phase C: local exclusive scan + block offset -> rowptr, cursor ---
__global__ __launch_bounds__(256) void scanC_kernel(const int* __restrict__ deg,
                                                    const int* __restrict__ bsum,
                                                    int* __restrict__ rowptr,
                                                    int* __restrict__ cursor, int n, int E)
{
    __shared__ int tsum[256];
    int t = threadIdx.x;
    int tb = blockIdx.x * SCAN_CHUNK + t * 8;
    int v[8];
    int s = 0;
#pragma unroll
    for (int k = 0; k < 8; k++) {
        int idx = tb + k;
        v[k] = (idx < n) ? deg[idx] : 0;
        s += v[k];
    }
    tsum[t] = s;
    __syncthreads();
    for (int off = 1; off < 256; off <<= 1) {
        int u = (t >= off) ? tsum[t - off] : 0;
        __syncthreads();
        tsum[t] += u;
        __syncthreads();
    }
    int run = bsum[blockIdx.x] + tsum[t] - s;
#pragma unroll
    for (int k = 0; k < 8; k++) {
        int idx = tb + k;
        if (idx < n) { rowptr[idx] = run; cursor[idx] = run; run += v[k]; }
    }
    if (blockIdx.x == 0 && t == 0) rowptr[n] = E;
}

// ---- CSR build: bucket edges by dst ----------------------------------------
__global__ void fill_kernel(const int* __restrict__ src, const int* __restrict__ dst,
                            int* __restrict__ cursor, int* __restrict__ col, int E)
{
    int e = blockIdx.x * 256 + threadIdx.x;
    if (e < E) {
        int p = atomicAdd(&cursor[dst[e]], 1);
        col[p] = src[e];
    }
}

// ---- gather aggregation over bf16 rows, 8 gathers in flight ----------------
// aggb[node] = bf16( mean of featb[col[rowptr[node]..rowptr[node+1])] )
__global__ __launch_bounds__(256) void agg_kernel(const int* __restrict__ rowptr,
                                                  const int* __restrict__ col,
                                                  const uint* __restrict__ featb,
                                                  uint* __restrict__ aggb, int n)
{
    int node = blockIdx.x * 4 + (threadIdx.x >> 6);
    if (node >= n) return;
    int lane = threadIdx.x & 63;
    int r0 = rowptr[node], r1 = rowptr[node + 1];
    const uint* fb = featb + lane;
    float sx = 0.f, sy = 0.f;
    int i = r0;
    for (; i + 8 <= r1; i += 8) {
        int c0 = col[i + 0], c1 = col[i + 1], c2 = col[i + 2], c3 = col[i + 3];
        int c4 = col[i + 4], c5 = col[i + 5], c6 = col[i + 6], c7 = col[i + 7];
        uint v0 = fb[(size_t)c0 << 6];
        uint v1 = fb[(size_t)c1 << 6];
        uint v2 = fb[(size_t)c2 << 6];
        uint v3 = fb[(size_t)c3 << 6];
        uint v4 = fb[(size_t)c4 << 6];
        uint v5 = fb[(size_t)c5 << 6];
        uint v6 = fb[(size_t)c6 << 6];
        uint v7 = fb[(size_t)c7 << 6];
        sx += bf_lo(v0) + bf_lo(v1) + bf_lo(v2) + bf_lo(v3)
            + bf_lo(v4) + bf_lo(v5) + bf_lo(v6) + bf_lo(v7);
        sy += bf_hi(v0) + bf_hi(v1) + bf_hi(v2) + bf_hi(v3)
            + bf_hi(v4) + bf_hi(v5) + bf_hi(v6) + bf_hi(v7);
    }
    for (; i < r1; i++) {
        uint v = fb[(size_t)col[i] << 6];
        sx += bf_lo(v);
        sy += bf_hi(v);
    }
    float sc = 1.0f / fmaxf((float)(r1 - r0), 1.0f);
    aggb[(size_t)node * 64 + lane] = pack_bf16(sx * sc, sy * sc);
}

// ---- fused conv: out[n][j] = bias[j] + p1[n]·wl[j] + p2[n]·wr[j] -----------
// p1b/p2b are bf16-packed rows (64 uints = 128 feats); out fp32.
__global__ __launch_bounds__(256) void conv_kernel(
    const uint* __restrict__ p1b, const uint* __restrict__ p2b,
    const float* __restrict__ wT, const float* __restrict__ bias,
    float* __restrict__ out, int n_nodes)
{
    __shared__ float a[32][256];
    int nb = blockIdx.x * 32;
    for (int q = threadIdx.x; q < 2048; q += 256) {
        int m = q >> 6;
        int kq = q & 63;
        int node = nb + m;
        float4 v = make_float4(0.f, 0.f, 0.f, 0.f);
        if (node < n_nodes) {
            const uint* srcb = (kq < 32) ? p1b : p2b;
            uint2 u = ((const uint2*)(srcb + (size_t)node * 64))[kq & 31];
            v = make_float4(bf_lo(u.x), bf_hi(u.x), bf_lo(u.y), bf_hi(u.y));
        }
        ((float4*)&a[m][0])[kq] = v;
    }
    __syncthreads();

    int j4 = (threadIdx.x & 31) * 4;
    int mBase = threadIdx.x >> 5;
    float b0 = bias[j4], b1 = bias[j4 + 1], b2 = bias[j4 + 2], b3 = bias[j4 + 3];
    float acc[4][4];
#pragma unroll
    for (int i = 0; i < 4; i++) { acc[i][0] = b0; acc[i][1] = b1; acc[i][2] = b2; acc[i][3] = b3; }

    for (int k = 0; k < 256; k += 4) {
        float4 w0 = *(const float4*)&wT[(k + 0) * D + j4];
        float4 w1 = *(const float4*)&wT[(k + 1) * D + j4];
        float4 w2 = *(const float4*)&wT[(k + 2) * D + j4];
        float4 w3 = *(const float4*)&wT[(k + 3) * D + j4];
#pragma unroll
        for (int i = 0; i < 4; i++) {
            float4 av = *(const float4*)&a[mBase + i * 8][k];
            acc[i][0] += av.x * w0.x + av.y * w1.x + av.z * w2.x + av.w * w3.x;
            acc[i][1] += av.x * w0.y + av.y * w1.y + av.z * w2.y + av.w * w3.y;
            acc[i][2] += av.x * w0.z + av.y * w1.z + av.z * w2.z + av.w * w3.z;
            acc[i][3] += av.x * w0.w + av.y * w1.w + av.z * w2.w + av.w * w3.w;
        }
    }
#pragma unroll
    for (int i = 0; i < 4; i++) {
        int node = nb + mBase + i * 8;
        if (node < n_nodes) {
            float4 o = make_float4(acc[i][0], acc[i][1], acc[i][2], acc[i][3]);
            ((float4*)(out + (size_t)node * D))[j4 >> 2] = o;
        }
    }
}

// ---- per-feature column sum / sumsq (h fp32) -------------------------------
__global__ void stats_kernel(const float* __restrict__ h, float* __restrict__ stats, int n)
{
    int j = threadIdx.x & 127;
    int half = threadIdx.x >> 7;
    float s = 0.f, ss = 0.f;
    for (int r = blockIdx.x * 2 + half; r < n; r += gridDim.x * 2) {
        float v = h[(size_t)r * D + j];
        s += v;
        ss += v * v;
    }
    __shared__ float buf[512];
    buf[threadIdx.x] = s;
    buf[256 + threadIdx.x] = ss;
    __syncthreads();
    if (threadIdx.x < 128) {
        s = buf[threadIdx.x] + buf[threadIdx.x + 128];
        ss = buf[256 + threadIdx.x] + buf[256 + threadIdx.x + 128];
        unsafeAtomicAdd(&stats[j], s);
        unsafeAtomicAdd(&stats[128 + j], ss);
    }
}

// ---- BN finalize + apply + relu + bf16 pack: h(fp32) -> hb(bf16) -----------
__global__ __launch_bounds__(256) void bnapply_kernel(const float* __restrict__ h,
                                                      const float* __restrict__ stats,
                                                      const float* __restrict__ gamma,
                                                      const float* __restrict__ beta,
                                                      uint* __restrict__ hb,
                                                      float n_inv, int total4)
{
    __shared__ float sc[128], sh[128];
    if (threadIdx.x < 128) {
        int j = threadIdx.x;
        float mean = stats[j] * n_inv;
        float var = fmaxf(stats[128 + j] * n_inv - mean * mean, 0.f);
        float s = gamma[j] * rsqrtf(var + EPS);
        sc[j] = s;
        sh[j] = beta[j] - mean * s;
    }
    __syncthreads();
    int idx = blockIdx.x * 256 + threadIdx.x;
    if (idx >= total4) return;
    int j4 = (idx & 31) * 4;
    float4 v = ((const float4*)h)[idx];
    v.x = fmaxf(v.x * sc[j4 + 0] + sh[j4 + 0], 0.f);
    v.y = fmaxf(v.y * sc[j4 + 1] + sh[j4 + 1], 0.f);
    v.z = fmaxf(v.z * sc[j4 + 2] + sh[j4 + 2], 0.f);
    v.w = fmaxf(v.w * sc[j4 + 3] + sh[j4 + 3], 0.f);
    uint2 o;
    o.x = pack_bf16(v.x, v.y);
    o.y = pack_bf16(v.z, v.w);
    ((uint2*)hb)[idx] = o;
}

extern "C" void kernel_launch(void* const* d_in, const int* in_sizes, int n_in,
                              void* d_out, int out_size, void* d_ws, size_t ws_size,
                              hipStream_t stream)
{
    const float* x     = (const float*)d_in[0];
    const int*   ei    = (const int*)d_in[1];
    const float* w1_l  = (const float*)d_in[2];
    const float* b1_l  = (const float*)d_in[3];
    const float* w1_r  = (const float*)d_in[4];
    const float* w2_l  = (const float*)d_in[5];
    const float* b2_l  = (const float*)d_in[6];
    const float* w2_r  = (const float*)d_in[7];
    const float* gamma = (const float*)d_in[8];
    const float* beta  = (const float*)d_in[9];

    int N = in_sizes[0] / D;
    int E = in_sizes[1] / 2;
    const int* src = ei;
    const int* dst = ei + E;

    // workspace layout (16B-aligned chunks first):
    // uints: aggb[N*64] | xb[N*64] | hb[N*64]
    // floats: wT1[32768] | wT2[32768] | stats[256]
    // ints: deg[N] | rowptr[N+1] | cursor[N] | col[E] | bsum[64]
    uint*  aggb   = (uint*)d_ws;
    uint*  xb     = aggb + (size_t)N * 64;
    uint*  hb     = xb + (size_t)N * 64;
    float* wT1    = (float*)(hb + (size_t)N * 64);
    float* wT2    = wT1 + 32768;
    float* stats  = wT2 + 32768;
    int*   deg    = (int*)(stats + 256);
    int*   rowptr = deg + N;
    int*   cursor = rowptr + N + 1;
    int*   col    = cursor + N;
    int*   bsum   = col + E;

    float* h = (float*)d_out;   // fp32 hidden lives in d_out between conv1 and bnapply

    hipMemsetAsync(deg, 0, (size_t)N * sizeof(int), stream);
    hipMemsetAsync(stats, 0, 256 * sizeof(float), stream);

    int ncvt = N * 32;                           // float4 slots for x
    int pblocks = (ncvt + 65536 + 255) / 256;
    prep_kernel<<<pblocks, 256, 0, stream>>>(x, xb, ncvt, w1_l, w1_r, w2_l, w2_r, wT1, wT2);

    int eblocks = (E + 255) / 256;
    int ablocks = (N + 3) / 4;
    int cblocks = (N + 31) / 32;
    int nscan   = (N + SCAN_CHUNK - 1) / SCAN_CHUNK;

    // CSR build (shared by both layers)
    hist_kernel<<<eblocks, 256, 0, stream>>>(dst, deg, E);
    scanA_kernel<<<nscan, 256, 0, stream>>>(deg, bsum, N);
    scanB_kernel<<<1, 64, 0, stream>>>(bsum, nscan);
    scanC_kernel<<<nscan, 256, 0, stream>>>(deg, bsum, rowptr, cursor, N, E);
    fill_kernel<<<eblocks, 256, 0, stream>>>(src, dst, cursor, col, E);

    // layer 1
    agg_kernel<<<ablocks, 256, 0, stream>>>(rowptr, col, xb, aggb, N);
    conv_kernel<<<cblocks, 256, 0, stream>>>(aggb, xb, wT1, b1_l, h, N);

    // batch norm + relu -> bf16 hb
    stats_kernel<<<256, 256, 0, stream>>>(h, stats, N);
    bnapply_kernel<<<(N * 32 + 255) / 256, 256, 0, stream>>>(h, stats, gamma, beta, hb,
                                                             1.0f / (float)N, N * 32);

    // layer 2
    agg_kernel<<<ablocks, 256, 0, stream>>>(rowptr, col, hb, aggb, N);
    conv_kernel<<<cblocks, 256, 0, stream>>>(aggb, hb, wT2, b2_l, (float*)d_out, N);
}

// Round 5
// 342.013 us; speedup vs baseline: 8.7964x; 1.2666x over previous
//
#include <hip/hip_runtime.h>

#define D 128
#define EPS 1e-5f
#define SCAN_CHUNK 2048

typedef unsigned int uint;
typedef __attribute__((ext_vector_type(4))) float f32x4;
typedef __attribute__((ext_vector_type(8))) short s16x8;

// ---- bf16 pack/unpack helpers (RTNE) ---------------------------------------
__device__ __forceinline__ uint pack_bf16(float a, float b)
{
    uint ua = __float_as_uint(a);
    uint ub = __float_as_uint(b);
    ua += 0x7FFFu + ((ua >> 16) & 1u);
    ub += 0x7FFFu + ((ub >> 16) & 1u);
    return (ua >> 16) | (ub & 0xFFFF0000u);
}
__device__ __forceinline__ float bf_lo(uint v) { return __uint_as_float(v << 16); }
__device__ __forceinline__ float bf_hi(uint v) { return __uint_as_float(v & 0xFFFF0000u); }

// ---- prep: x -> xb (bf16) AND wb1/wb2 (bf16, MFMA B-fragment order) --------
// B-frag layout (16x16x32): lane l holds B[k=kstep*32+(l>>4)*8+j][n=nt*16+(l&15)],
// j=0..7 packed in a uint4. Stored at uint4 index (kstep*8+nt)*64 + l.
__global__ void prep_kernel(const float* __restrict__ x, uint* __restrict__ xb, int ncvt,
                            const float* __restrict__ w1l, const float* __restrict__ w1r,
                            const float* __restrict__ w2l, const float* __restrict__ w2r,
                            uint* __restrict__ wb1, uint* __restrict__ wb2)
{
    int idx = blockIdx.x * 256 + threadIdx.x;
    if (idx < ncvt) {
        float4 v = ((const float4*)x)[idx];
        uint2 o;
        o.x = pack_bf16(v.x, v.y);
        o.y = pack_bf16(v.z, v.w);
        ((uint2*)xb)[idx] = o;
    } else {
        int r = idx - ncvt;          // 0..8191
        if (r < 8192) {
            int layer = r >> 12;
            int rem = r & 4095;
            int lane = rem & 63;
            int knt = rem >> 6;          // 0..63
            int kstep = knt >> 3, nt = knt & 7;
            int nn = nt * 16 + (lane & 15);
            int kbase = kstep * 32 + (lane >> 4) * 8;
            const float* wl = layer ? w2l : w1l;
            const float* wr = layer ? w2r : w1r;
            uint* wb = layer ? wb2 : wb1;
            float v[8];
#pragma unroll
            for (int j = 0; j < 8; j++) {
                int k = kbase + j;
                v[j] = (k < D) ? wl[nn * D + k] : wr[nn * D + (k - D)];
            }
            uint4 o;
            o.x = pack_bf16(v[0], v[1]);
            o.y = pack_bf16(v[2], v[3]);
            o.z = pack_bf16(v[4], v[5]);
            o.w = pack_bf16(v[6], v[7]);
            ((uint4*)wb)[(kstep * 8 + nt) * 64 + lane] = o;
        }
    }
}

// ---- CSR build: degree histogram -------------------------------------------
__global__ void hist_kernel(const int* __restrict__ dst, int* __restrict__ deg, int E)
{
    int e = blockIdx.x * 256 + threadIdx.x;
    if (e < E) atomicAdd(&deg[dst[e]], 1);
}

// ---- scan phase A: per-block (2048-chunk) sums ------------------------------
__global__ __launch_bounds__(256) void scanA_kernel(const int* __restrict__ deg,
                                                    int* __restrict__ bsum, int n)
{
    __shared__ int red[256];
    int base = blockIdx.x * SCAN_CHUNK;
    int s = 0;
    for (int i = threadIdx.x; i < SCAN_CHUNK; i += 256) {
        int idx = base + i;
        if (idx < n) s += deg[idx];
    }
    red[threadIdx.x] = s;
    __syncthreads();
    for (int off = 128; off > 0; off >>= 1) {
        if (threadIdx.x < off) red[threadIdx.x] += red[threadIdx.x + off];
        __syncthreads();
    }
    if (threadIdx.x == 0) bsum[blockIdx.x] = red[0];
}

// ---- scan phase B: one wave, exclusive scan of block sums (nb <= 64) -------
__global__ void scanB_kernel(int* __restrict__ bsum, int nb)
{
    int t = threadIdx.x;
    int v = (t < nb) ? bsum[t] : 0;
    for (int off = 1; off < 64; off <<= 1) {
        int u = __shfl_up(v, off);
        if (t >= off) v += u;
    }
    int ex = __shfl_up(v, 1);
    if (t == 0) ex = 0;
    if (t < nb) bsum[t] = ex;
}

// ---- scan phase C: local exclusive scan + block offset -> rowptr, cursor ---
__global__ __launch_bounds__(256) void scanC_kernel(const int* __restrict__ deg,
                                                    const int* __restrict__ bsum,
                                                    int* __restrict__ rowptr,
                                                    int* __restrict__ cursor, int n, int E)
{
    __shared__ int tsum[256];
    int t = threadIdx.x;
    int tb = blockIdx.x * SCAN_CHUNK + t * 8;
    int v[8];
    int s = 0;
#pragma unroll
    for (int k = 0; k < 8; k++) {
        int idx = tb + k;
        v[k] = (idx < n) ? deg[idx] : 0;
        s += v[k];
    }
    tsum[t] = s;
    __syncthreads();
    for (int off = 1; off < 256; off <<= 1) {
        int u = (t >= off) ? tsum[t - off] : 0;
        __syncthreads();
        tsum[t] += u;
        __syncthreads();
    }
    int run = bsum[blockIdx.x] + tsum[t] - s;
#pragma unroll
    for (int k = 0; k < 8; k++) {
        int idx = tb + k;
        if (idx < n) { rowptr[idx] = run; cursor[idx] = run; run += v[k]; }
    }
    if (blockIdx.x == 0 && t == 0) rowptr[n] = E;
}

// ---- CSR build: bucket edges by dst ----------------------------------------
__global__ void fill_kernel(const int* __restrict__ src, const int* __restrict__ dst,
                            int* __restrict__ cursor, int* __restrict__ col, int E)
{
    int e = blockIdx.x * 256 + threadIdx.x;
    if (e < E) {
        int p = atomicAdd(&cursor[dst[e]], 1);
        col[p] = src[e];
    }
}

// ---- gather aggregation over bf16 rows, 8 gathers in flight ----------------
__global__ __launch_bounds__(256) void agg_kernel(const int* __restrict__ rowptr,
                                                  const int* __restrict__ col,
                                                  const uint* __restrict__ featb,
                                                  uint* __restrict__ aggb, int n)
{
    int node = blockIdx.x * 4 + (threadIdx.x >> 6);
    if (node >= n) return;
    int lane = threadIdx.x & 63;
    int r0 = rowptr[node], r1 = rowptr[node + 1];
    const uint* fb = featb + lane;
    float sx = 0.f, sy = 0.f;
    int i = r0;
    for (; i + 8 <= r1; i += 8) {
        int c0 = col[i + 0], c1 = col[i + 1], c2 = col[i + 2], c3 = col[i + 3];
        int c4 = col[i + 4], c5 = col[i + 5], c6 = col[i + 6], c7 = col[i + 7];
        uint v0 = fb[(size_t)c0 << 6];
        uint v1 = fb[(size_t)c1 << 6];
        uint v2 = fb[(size_t)c2 << 6];
        uint v3 = fb[(size_t)c3 << 6];
        uint v4 = fb[(size_t)c4 << 6];
        uint v5 = fb[(size_t)c5 << 6];
        uint v6 = fb[(size_t)c6 << 6];
        uint v7 = fb[(size_t)c7 << 6];
        sx += bf_lo(v0) + bf_lo(v1) + bf_lo(v2) + bf_lo(v3)
            + bf_lo(v4) + bf_lo(v5) + bf_lo(v6) + bf_lo(v7);
        sy += bf_hi(v0) + bf_hi(v1) + bf_hi(v2) + bf_hi(v3)
            + bf_hi(v4) + bf_hi(v5) + bf_hi(v6) + bf_hi(v7);
    }
    for (; i < r1; i++) {
        uint v = fb[(size_t)col[i] << 6];
        sx += bf_lo(v);
        sy += bf_hi(v);
    }
    float sc = 1.0f / fmaxf((float)(r1 - r0), 1.0f);
    aggb[(size_t)node * 64 + lane] = pack_bf16(sx * sc, sy * sc);
}

// ---- MFMA conv: out[64 nodes][128 cols] per block --------------------------
// A row n = [p1b row (k 0..127) | p2b row (k 128..255)], bf16.
// 4 waves; wave w owns cols [w*32, w*32+32) = B ntiles {2w, 2w+1}.
// 16x16x32 bf16 MFMA; layouts per guide (m89/m91-verified).
__global__ __launch_bounds__(256) void conv_kernel(
    const uint* __restrict__ p1b, const uint* __restrict__ p2b,
    const uint* __restrict__ wb, const float* __restrict__ bias,
    float* __restrict__ out, int n)
{
    int w = threadIdx.x >> 6;
    int lane = threadIdx.x & 63;
    int quad = lane >> 4;
    int l15 = lane & 15;
    int nb = blockIdx.x * 64;

    const uint4* p1 = (const uint4*)p1b;   // 16 uint4 per row
    const uint4* p2 = (const uint4*)p2b;
    const uint4* wv = (const uint4*)wb;

    // B fragments: 8 ksteps x 2 ntiles (64 VGPRs)
    uint4 B[8][2];
    int nt0 = w * 2;
#pragma unroll
    for (int ks = 0; ks < 8; ks++) {
#pragma unroll
        for (int t = 0; t < 2; t++)
            B[ks][t] = wv[(ks * 8 + nt0 + t) * 64 + lane];
    }

    float bv0 = bias[nt0 * 16 + l15];
    float bv1 = bias[nt0 * 16 + 16 + l15];

    for (int rt = 0; rt < 4; rt++) {
        int node = nb + rt * 16 + l15;
        int nc = min(node, n - 1);
        uint4 A[8];
#pragma unroll
        for (int ks = 0; ks < 4; ks++) A[ks] = p1[(size_t)nc * 16 + ks * 4 + quad];
#pragma unroll
        for (int ks = 0; ks < 4; ks++) A[ks + 4] = p2[(size_t)nc * 16 + ks * 4 + quad];

        f32x4 acc0 = {bv0, bv0, bv0, bv0};
        f32x4 acc1 = {bv1, bv1, bv1, bv1};
#pragma unroll
        for (int ks = 0; ks < 8; ks++) {
            s16x8 a = *(s16x8*)&A[ks];
            acc0 = __builtin_amdgcn_mfma_f32_16x16x32_bf16(a, *(s16x8*)&B[ks][0], acc0, 0, 0, 0);
            acc1 = __builtin_amdgcn_mfma_f32_16x16x32_bf16(a, *(s16x8*)&B[ks][1], acc1, 0, 0, 0);
        }
        // C/D: col = lane&15, row = quad*4 + reg
        int row0 = nb + rt * 16 + quad * 4;
        int colbase = nt0 * 16 + l15;
#pragma unroll
        for (int reg = 0; reg < 4; reg++) {
            int row = row0 + reg;
            if (row < n) {
                out[(size_t)row * D + colbase] = acc0[reg];
                out[(size_t)row * D + colbase + 16] = acc1[reg];
            }
        }
    }
}

// ---- per-feature column sum / sumsq (h fp32) -------------------------------
__global__ void stats_kernel(const float* __restrict__ h, float* __restrict__ stats, int n)
{
    int j = threadIdx.x & 127;
    int half = threadIdx.x >> 7;
    float s = 0.f, ss = 0.f;
    for (int r = blockIdx.x * 2 + half; r < n; r += gridDim.x * 2) {
        float v = h[(size_t)r * D + j];
        s += v;
        ss += v * v;
    }
    __shared__ float buf[512];
    buf[threadIdx.x] = s;
    buf[256 + threadIdx.x] = ss;
    __syncthreads();
    if (threadIdx.x < 128) {
        s = buf[threadIdx.x] + buf[threadIdx.x + 128];
        ss = buf[256 + threadIdx.x] + buf[256 + threadIdx.x + 128];
        unsafeAtomicAdd(&stats[j], s);
        unsafeAtomicAdd(&stats[128 + j], ss);
    }
}

// ---- BN finalize + apply + relu + bf16 pack: h(fp32) -> hb(bf16) -----------
__global__ __launch_bounds__(256) void bnapply_kernel(const float* __restrict__ h,
                                                      const float* __restrict__ stats,
                                                      const float* __restrict__ gamma,
                                                      const float* __restrict__ beta,
                                                      uint* __restrict__ hb,
                                                      float n_inv, int total4)
{
    __shared__ float sc[128], sh[128];
    if (threadIdx.x < 128) {
        int j = threadIdx.x;
        float mean = stats[j] * n_inv;
        float var = fmaxf(stats[128 + j] * n_inv - mean * mean, 0.f);
        float s = gamma[j] * rsqrtf(var + EPS);
        sc[j] = s;
        sh[j] = beta[j] - mean * s;
    }
    __syncthreads();
    int idx = blockIdx.x * 256 + threadIdx.x;
    if (idx >= total4) return;
    int j4 = (idx & 31) * 4;
    float4 v = ((const float4*)h)[idx];
    v.x = fmaxf(v.x * sc[j4 + 0] + sh[j4 + 0], 0.f);
    v.y = fmaxf(v.y * sc[j4 + 1] + sh[j4 + 1], 0.f);
    v.z = fmaxf(v.z * sc[j4 + 2] + sh[j4 + 2], 0.f);
    v.w = fmaxf(v.w * sc[j4 + 3] + sh[j4 + 3], 0.f);
    uint2 o;
    o.x = pack_bf16(v.x, v.y);
    o.y = pack_bf16(v.z, v.w);
    ((uint2*)hb)[idx] = o;
}

extern "C" void kernel_launch(void* const* d_in, const int* in_sizes, int n_in,
                              void* d_out, int out_size, void* d_ws, size_t ws_size,
                              hipStream_t stream)
{
    const float* x     = (const float*)d_in[0];
    const int*   ei    = (const int*)d_in[1];
    const float* w1_l  = (const float*)d_in[2];
    const float* b1_l  = (const float*)d_in[3];
    const float* w1_r  = (const float*)d_in[4];
    const float* w2_l  = (const float*)d_in[5];
    const float* b2_l  = (const float*)d_in[6];
    const float* w2_r  = (const float*)d_in[7];
    const float* gamma = (const float*)d_in[8];
    const float* beta  = (const float*)d_in[9];

    int N = in_sizes[0] / D;
    int E = in_sizes[1] / 2;
    const int* src = ei;
    const int* dst = ei + E;

    // workspace layout (16B-aligned chunks first):
    // uints: aggb[N*64] | xb[N*64] | hb[N*64] | wb1[16384] | wb2[16384]
    // floats: stats[256]
    // ints: deg[N] | rowptr[N+1] | cursor[N] | col[E] | bsum[64]
    uint*  aggb   = (uint*)d_ws;
    uint*  xb     = aggb + (size_t)N * 64;
    uint*  hb     = xb + (size_t)N * 64;
    uint*  wb1    = hb + (size_t)N * 64;
    uint*  wb2    = wb1 + 16384;
    float* stats  = (float*)(wb2 + 16384);
    int*   deg    = (int*)(stats + 256);
    int*   rowptr = deg + N;
    int*   cursor = rowptr + N + 1;
    int*   col    = cursor + N;
    int*   bsum   = col + E;

    float* h = (float*)d_out;   // fp32 hidden lives in d_out between conv1 and bnapply

    hipMemsetAsync(deg, 0, (size_t)N * sizeof(int), stream);
    hipMemsetAsync(stats, 0, 256 * sizeof(float), stream);

    int ncvt = N * 32;                           // float4 slots for x
    int pblocks = (ncvt + 8192 + 255) / 256;
    prep_kernel<<<pblocks, 256, 0, stream>>>(x, xb, ncvt, w1_l, w1_r, w2_l, w2_r, wb1, wb2);

    int eblocks = (E + 255) / 256;
    int ablocks = (N + 3) / 4;
    int cblocks = (N + 63) / 64;
    int nscan   = (N + SCAN_CHUNK - 1) / SCAN_CHUNK;

    // CSR build (shared by both layers)
    hist_kernel<<<eblocks, 256, 0, stream>>>(dst, deg, E);
    scanA_kernel<<<nscan, 256, 0, stream>>>(deg, bsum, N);
    scanB_kernel<<<1, 64, 0, stream>>>(bsum, nscan);
    scanC_kernel<<<nscan, 256, 0, stream>>>(deg, bsum, rowptr, cursor, N, E);
    fill_kernel<<<eblocks, 256, 0, stream>>>(src, dst, cursor, col, E);

    // layer 1
    agg_kernel<<<ablocks, 256, 0, stream>>>(rowptr, col, xb, aggb, N);
    conv_kernel<<<cblocks, 256, 0, stream>>>(aggb, xb, wb1, b1_l, h, N);

    // batch norm + relu -> bf16 hb
    stats_kernel<<<256, 256, 0, stream>>>(h, stats, N);
    bnapply_kernel<<<(N * 32 + 255) / 256, 256, 0, stream>>>(h, stats, gamma, beta, hb,
                                                             1.0f / (float)N, N * 32);

    // layer 2
    agg_kernel<<<ablocks, 256, 0, stream>>>(rowptr, col, hb, aggb, N);
    conv_kernel<<<cblocks, 256, 0, stream>>>(aggb, hb, wb2, b2_l, (float*)d_out, N);
}

// Round 6
// 333.558 us; speedup vs baseline: 9.0194x; 1.0253x over previous
//
#include <hip/hip_runtime.h>

#define D 128
#define EPS 1e-5f
#define SCAN_CHUNK 2048

typedef unsigned int uint;
typedef __attribute__((ext_vector_type(4))) float f32x4;
typedef __attribute__((ext_vector_type(8))) short s16x8;

// ---- bf16 pack/unpack helpers (RTNE) ---------------------------------------
__device__ __forceinline__ uint pack_bf16(float a, float b)
{
    uint ua = __float_as_uint(a);
    uint ub = __float_as_uint(b);
    ua += 0x7FFFu + ((ua >> 16) & 1u);
    ub += 0x7FFFu + ((ub >> 16) & 1u);
    return (ua >> 16) | (ub & 0xFFFF0000u);
}
__device__ __forceinline__ float bf_lo(uint v) { return __uint_as_float(v << 16); }
__device__ __forceinline__ float bf_hi(uint v) { return __uint_as_float(v & 0xFFFF0000u); }

// ---- prep: x -> xb (bf16) AND wb1/wb2 (bf16, MFMA B-fragment order) --------
__global__ void prep_kernel(const float* __restrict__ x, uint* __restrict__ xb, int ncvt,
                            const float* __restrict__ w1l, const float* __restrict__ w1r,
                            const float* __restrict__ w2l, const float* __restrict__ w2r,
                            uint* __restrict__ wb1, uint* __restrict__ wb2)
{
    int idx = blockIdx.x * 256 + threadIdx.x;
    if (idx < ncvt) {
        float4 v = ((const float4*)x)[idx];
        uint2 o;
        o.x = pack_bf16(v.x, v.y);
        o.y = pack_bf16(v.z, v.w);
        ((uint2*)xb)[idx] = o;
    } else {
        int r = idx - ncvt;          // 0..8191
        if (r < 8192) {
            int layer = r >> 12;
            int rem = r & 4095;
            int lane = rem & 63;
            int knt = rem >> 6;
            int kstep = knt >> 3, nt = knt & 7;
            int nn = nt * 16 + (lane & 15);
            int kbase = kstep * 32 + (lane >> 4) * 8;
            const float* wl = layer ? w2l : w1l;
            const float* wr = layer ? w2r : w1r;
            uint* wb = layer ? wb2 : wb1;
            float v[8];
#pragma unroll
            for (int j = 0; j < 8; j++) {
                int k = kbase + j;
                v[j] = (k < D) ? wl[nn * D + k] : wr[nn * D + (k - D)];
            }
            uint4 o;
            o.x = pack_bf16(v[0], v[1]);
            o.y = pack_bf16(v[2], v[3]);
            o.z = pack_bf16(v[4], v[5]);
            o.w = pack_bf16(v[6], v[7]);
            ((uint4*)wb)[(kstep * 8 + nt) * 64 + lane] = o;
        }
    }
}

// ---- CSR build --------------------------------------------------------------
__global__ void hist_kernel(const int* __restrict__ dst, int* __restrict__ deg, int E)
{
    int e = blockIdx.x * 256 + threadIdx.x;
    if (e < E) atomicAdd(&deg[dst[e]], 1);
}

__global__ __launch_bounds__(256) void scanA_kernel(const int* __restrict__ deg,
                                                    int* __restrict__ bsum, int n)
{
    __shared__ int red[256];
    int base = blockIdx.x * SCAN_CHUNK;
    int s = 0;
    for (int i = threadIdx.x; i < SCAN_CHUNK; i += 256) {
        int idx = base + i;
        if (idx < n) s += deg[idx];
    }
    red[threadIdx.x] = s;
    __syncthreads();
    for (int off = 128; off > 0; off >>= 1) {
        if (threadIdx.x < off) red[threadIdx.x] += red[threadIdx.x + off];
        __syncthreads();
    }
    if (threadIdx.x == 0) bsum[blockIdx.x] = red[0];
}

__global__ void scanB_kernel(int* __restrict__ bsum, int nb)
{
    int t = threadIdx.x;
    int v = (t < nb) ? bsum[t] : 0;
    for (int off = 1; off < 64; off <<= 1) {
        int u = __shfl_up(v, off);
        if (t >= off) v += u;
    }
    int ex = __shfl_up(v, 1);
    if (t == 0) ex = 0;
    if (t < nb) bsum[t] = ex;
}

__global__ __launch_bounds__(256) void scanC_kernel(const int* __restrict__ deg,
                                                    const int* __restrict__ bsum,
                                                    int* __restrict__ rowptr,
                                                    int* __restrict__ cursor, int n, int E)
{
    __shared__ int tsum[256];
    int t = threadIdx.x;
    int tb = blockIdx.x * SCAN_CHUNK + t * 8;
    int v[8];
    int s = 0;
#pragma unroll
    for (int k = 0; k < 8; k++) {
        int idx = tb + k;
        v[k] = (idx < n) ? deg[idx] : 0;
        s += v[k];
    }
    tsum[t] = s;
    __syncthreads();
    for (int off = 1; off < 256; off <<= 1) {
        int u = (t >= off) ? tsum[t - off] : 0;
        __syncthreads();
        tsum[t] += u;
        __syncthreads();
    }
    int run = bsum[blockIdx.x] + tsum[t] - s;
#pragma unroll
    for (int k = 0; k < 8; k++) {
        int idx = tb + k;
        if (idx < n) { rowptr[idx] = run; cursor[idx] = run; run += v[k]; }
    }
    if (blockIdx.x == 0 && t == 0) rowptr[n] = E;
}

__global__ void fill_kernel(const int* __restrict__ src, const int* __restrict__ dst,
                            int* __restrict__ cursor, int* __restrict__ col, int E)
{
    int e = blockIdx.x * 256 + threadIdx.x;
    if (e < E) {
        int p = atomicAdd(&cursor[dst[e]], 1);
        col[p] = src[e];
    }
}

// ---- gather aggregation, uint4 4-row gathers, optional inline BN+ReLU ------
// Wave per node. lane = sub*16 + l16; lane covers cols 8*l16..8*l16+7.
// Main loop: 16 neighbors/iter, 4 uint4 loads/lane = 4 KB in flight per wave.
template<bool BN>
__global__ __launch_bounds__(256) void agg_kernel(const int* __restrict__ rowptr,
                                                  const int* __restrict__ col,
                                                  const uint* __restrict__ featb,
                                                  const float* __restrict__ scsh,
                                                  uint* __restrict__ aggb, int n)
{
    int node = blockIdx.x * 4 + (threadIdx.x >> 6);
    if (node >= n) return;
    int lane = threadIdx.x & 63;
    int sub = lane >> 4, l16 = lane & 15;
    int r0 = rowptr[node], r1 = rowptr[node + 1];
    uint4* out4 = (uint4*)aggb;
    if (r0 == r1) {
        if (lane < 16) out4[(size_t)node * 16 + l16] = make_uint4(0, 0, 0, 0);
        return;
    }
    float sc[8], sh[8];
    if (BN) {
        float4 s0 = ((const float4*)scsh)[l16 * 2];
        float4 s1 = ((const float4*)scsh)[l16 * 2 + 1];
        float4 t0 = ((const float4*)scsh)[32 + l16 * 2];
        float4 t1 = ((const float4*)scsh)[32 + l16 * 2 + 1];
        sc[0] = s0.x; sc[1] = s0.y; sc[2] = s0.z; sc[3] = s0.w;
        sc[4] = s1.x; sc[5] = s1.y; sc[6] = s1.z; sc[7] = s1.w;
        sh[0] = t0.x; sh[1] = t0.y; sh[2] = t0.z; sh[3] = t0.w;
        sh[4] = t1.x; sh[5] = t1.y; sh[6] = t1.z; sh[7] = t1.w;
    }
    float acc[8] = {0.f, 0.f, 0.f, 0.f, 0.f, 0.f, 0.f, 0.f};
    const uint4* fb = (const uint4*)featb;

    auto accum = [&](uint4 v) {
        float e[8] = {bf_lo(v.x), bf_hi(v.x), bf_lo(v.y), bf_hi(v.y),
                      bf_lo(v.z), bf_hi(v.z), bf_lo(v.w), bf_hi(v.w)};
#pragma unroll
        for (int j = 0; j < 8; j++) {
            float t = e[j];
            if (BN) t = fmaxf(t * sc[j] + sh[j], 0.f);
            acc[j] += t;
        }
    };

    int i = r0;
    for (; i + 16 <= r1; i += 16) {
        int c0 = col[i + sub], c1 = col[i + 4 + sub];
        int c2 = col[i + 8 + sub], c3 = col[i + 12 + sub];
        uint4 v0 = fb[(size_t)c0 * 16 + l16];
        uint4 v1 = fb[(size_t)c1 * 16 + l16];
        uint4 v2 = fb[(size_t)c2 * 16 + l16];
        uint4 v3 = fb[(size_t)c3 * 16 + l16];
        accum(v0); accum(v1); accum(v2); accum(v3);
    }
    for (; i < r1; i += 4) {
        int idx = i + sub;
        if (idx < r1) {
            uint4 v = fb[(size_t)col[idx] * 16 + l16];
            accum(v);
        }
    }
#pragma unroll
    for (int j = 0; j < 8; j++) {
        acc[j] += __shfl_down(acc[j], 32);
        acc[j] += __shfl_down(acc[j], 16);
    }
    if (lane < 16) {
        float inv = 1.0f / (float)(r1 - r0);
        uint4 o;
        o.x = pack_bf16(acc[0] * inv, acc[1] * inv);
        o.y = pack_bf16(acc[2] * inv, acc[3] * inv);
        o.z = pack_bf16(acc[4] * inv, acc[5] * inv);
        o.w = pack_bf16(acc[6] * inv, acc[7] * inv);
        out4[(size_t)node * 16 + l16] = o;
    }
}

// ---- MFMA conv --------------------------------------------------------------
// FUSE1: write bf16 hb + fused BN-stats atomics (via 64x132 LDS fp32 tile).
// BNP2: apply BN+ReLU inline to the p2 (root) A-fragments; write fp32 out.
#define TSTRIDE 132
template<bool FUSE1, bool BNP2>
__global__ __launch_bounds__(256) void conv_kernel(
    const uint* __restrict__ p1b, const uint* __restrict__ p2b,
    const uint* __restrict__ wb, const float* __restrict__ bias,
    const float* __restrict__ scsh, float* __restrict__ outf,
    uint* __restrict__ outb, float* __restrict__ stats, int n)
{
    extern __shared__ float smem[];   // FUSE1: tile[64][TSTRIDE]; BNP2: scs[256]
    float* tile = smem;
    float* scs = smem;
    int w = threadIdx.x >> 6, lane = threadIdx.x & 63;
    int quad = lane >> 4, l15 = lane & 15;
    int nb = blockIdx.x * 64;

    if (BNP2) {
        scs[threadIdx.x] = scsh[threadIdx.x];
        __syncthreads();
    }

    const uint4* p1 = (const uint4*)p1b;
    const uint4* p2 = (const uint4*)p2b;
    const uint4* wv = (const uint4*)wb;

    uint4 B[8][2];
    int nt0 = w * 2;
#pragma unroll
    for (int ks = 0; ks < 8; ks++) {
#pragma unroll
        for (int t = 0; t < 2; t++)
            B[ks][t] = wv[(ks * 8 + nt0 + t) * 64 + lane];
    }

    float bv0 = bias[nt0 * 16 + l15];
    float bv1 = bias[nt0 * 16 + 16 + l15];

    for (int rt = 0; rt < 4; rt++) {
        int node = nb + rt * 16 + l15;
        int nc = min(node, n - 1);
        uint4 A[8];
#pragma unroll
        for (int ks = 0; ks < 4; ks++) A[ks] = p1[(size_t)nc * 16 + ks * 4 + quad];
#pragma unroll
        for (int ks = 0; ks < 4; ks++) A[ks + 4] = p2[(size_t)nc * 16 + ks * 4 + quad];

        if (BNP2) {
#pragma unroll
            for (int ks = 4; ks < 8; ks++) {
                int c0 = (ks - 4) * 32 + quad * 8;
                uint4 u = A[ks];
                float e[8] = {bf_lo(u.x), bf_hi(u.x), bf_lo(u.y), bf_hi(u.y),
                              bf_lo(u.z), bf_hi(u.z), bf_lo(u.w), bf_hi(u.w)};
#pragma unroll
                for (int j = 0; j < 8; j++)
                    e[j] = fmaxf(e[j] * scs[c0 + j] + scs[128 + c0 + j], 0.f);
                u.x = pack_bf16(e[0], e[1]);
                u.y = pack_bf16(e[2], e[3]);
                u.z = pack_bf16(e[4], e[5]);
                u.w = pack_bf16(e[6], e[7]);
                A[ks] = u;
            }
        }

        f32x4 acc0 = {bv0, bv0, bv0, bv0};
        f32x4 acc1 = {bv1, bv1, bv1, bv1};
#pragma unroll
        for (int ks = 0; ks < 8; ks++) {
            s16x8 a = *(s16x8*)&A[ks];
            acc0 = __builtin_amdgcn_mfma_f32_16x16x32_bf16(a, *(s16x8*)&B[ks][0], acc0, 0, 0, 0);
            acc1 = __builtin_amdgcn_mfma_f32_16x16x32_bf16(a, *(s16x8*)&B[ks][1], acc1, 0, 0, 0);
        }
        // C/D: col = lane&15, row = quad*4 + reg
        int row0 = nb + rt * 16 + quad * 4;
        int colbase = nt0 * 16 + l15;
        if (FUSE1) {
            int rloc0 = rt * 16 + quad * 4;
#pragma unroll
            for (int reg = 0; reg < 4; reg++) {
                bool ok = (row0 + reg) < n;
                tile[(rloc0 + reg) * TSTRIDE + colbase]      = ok ? acc0[reg] : 0.f;
                tile[(rloc0 + reg) * TSTRIDE + colbase + 16] = ok ? acc1[reg] : 0.f;
            }
        } else {
#pragma unroll
            for (int reg = 0; reg < 4; reg++) {
                int row = row0 + reg;
                if (row < n) {
                    outf[(size_t)row * D + colbase] = acc0[reg];
                    outf[(size_t)row * D + colbase + 16] = acc1[reg];
                }
            }
        }
    }

    if (FUSE1) {
        __syncthreads();
        // per-block column sums over the fp32 tile (invalid rows are zero)
        int colj = threadIdx.x & 127, half = threadIdx.x >> 7;
        float s = 0.f, ss = 0.f;
        for (int r = half * 32; r < half * 32 + 32; r++) {
            float v = tile[r * TSTRIDE + colj];
            s += v;
            ss += v * v;
        }
        unsafeAtomicAdd(&stats[colj], s);
        unsafeAtomicAdd(&stats[128 + colj], ss);
        // pack tile -> bf16 hb
        uint4* ob4 = (uint4*)outb;
#pragma unroll
        for (int q4 = 0; q4 < 4; q4++) {
            int idx = q4 * 256 + threadIdx.x;   // 0..1023
            int r = idx >> 4, q = idx & 15;
            int row = nb + r;
            if (row < n) {
                float* tr = &tile[r * TSTRIDE + q * 8];
                uint4 o;
                o.x = pack_bf16(tr[0], tr[1]);
                o.y = pack_bf16(tr[2], tr[3]);
                o.z = pack_bf16(tr[4], tr[5]);
                o.w = pack_bf16(tr[6], tr[7]);
                ob4[(size_t)row * 16 + q] = o;
            }
        }
    }
}

// ---- BN scale/shift from stats ---------------------------------------------
__global__ void bnfin_kernel(const float* __restrict__ stats, const float* __restrict__ gamma,
                             const float* __restrict__ beta, float* __restrict__ scsh, float n_inv)
{
    int j = threadIdx.x;
    float mean = stats[j] * n_inv;
    float var = fmaxf(stats[128 + j] * n_inv - mean * mean, 0.f);
    float sc = gamma[j] * rsqrtf(var + EPS);
    scsh[j] = sc;
    scsh[128 + j] = beta[j] - mean * sc;
}

extern "C" void kernel_launch(void* const* d_in, const int* in_sizes, int n_in,
                              void* d_out, int out_size, void* d_ws, size_t ws_size,
                              hipStream_t stream)
{
    const float* x     = (const float*)d_in[0];
    const int*   ei    = (const int*)d_in[1];
    const float* w1_l  = (const float*)d_in[2];
    const float* b1_l  = (const float*)d_in[3];
    const float* w1_r  = (const float*)d_in[4];
    const float* w2_l  = (const float*)d_in[5];
    const float* b2_l  = (const float*)d_in[6];
    const float* w2_r  = (const float*)d_in[7];
    const float* gamma = (const float*)d_in[8];
    const float* beta  = (const float*)d_in[9];

    int N = in_sizes[0] / D;
    int E = in_sizes[1] / 2;
    const int* src = ei;
    const int* dst = ei + E;

    // workspace layout:
    // uints: aggb[N*64] | xb[N*64] | hb[N*64] | wb1[16384] | wb2[16384]
    // floats: stats[256] | scsh[256]
    // ints: deg[N] | rowptr[N+1] | cursor[N] | col[E] | bsum[64]
    uint*  aggb   = (uint*)d_ws;
    uint*  xb     = aggb + (size_t)N * 64;
    uint*  hb     = xb + (size_t)N * 64;
    uint*  wb1    = hb + (size_t)N * 64;
    uint*  wb2    = wb1 + 16384;
    float* stats  = (float*)(wb2 + 16384);
    float* scsh   = stats + 256;
    int*   deg    = (int*)(scsh + 256);
    int*   rowptr = deg + N;
    int*   cursor = rowptr + N + 1;
    int*   col    = cursor + N;
    int*   bsum   = col + E;

    hipMemsetAsync(deg, 0, (size_t)N * sizeof(int), stream);
    hipMemsetAsync(stats, 0, 256 * sizeof(float), stream);

    int ncvt = N * 32;
    int pblocks = (ncvt + 8192 + 255) / 256;
    prep_kernel<<<pblocks, 256, 0, stream>>>(x, xb, ncvt, w1_l, w1_r, w2_l, w2_r, wb1, wb2);

    int eblocks = (E + 255) / 256;
    int ablocks = (N + 3) / 4;
    int cblocks = (N + 63) / 64;
    int nscan   = (N + SCAN_CHUNK - 1) / SCAN_CHUNK;

    // CSR build (shared by both layers)
    hist_kernel<<<eblocks, 256, 0, stream>>>(dst, deg, E);
    scanA_kernel<<<nscan, 256, 0, stream>>>(deg, bsum, N);
    scanB_kernel<<<1, 64, 0, stream>>>(bsum, nscan);
    scanC_kernel<<<nscan, 256, 0, stream>>>(deg, bsum, rowptr, cursor, N, E);
    fill_kernel<<<eblocks, 256, 0, stream>>>(src, dst, cursor, col, E);

    // layer 1: agg + conv (conv writes bf16 hb and fused BN stats)
    agg_kernel<false><<<ablocks, 256, 0, stream>>>(rowptr, col, xb, nullptr, aggb, N);
    conv_kernel<true, false><<<cblocks, 256, 64 * TSTRIDE * 4, stream>>>(
        aggb, xb, wb1, b1_l, nullptr, nullptr, hb, stats, N);

    // BN scale/shift
    bnfin_kernel<<<1, 128, 0, stream>>>(stats, gamma, beta, scsh, 1.0f / (float)N);

    // layer 2: agg applies BN+ReLU inline; conv applies BN+ReLU to root term
    agg_kernel<true><<<ablocks, 256, 0, stream>>>(rowptr, col, hb, scsh, aggb, N);
    conv_kernel<false, true><<<cblocks, 256, 256 * 4, stream>>>(
        aggb, hb, wb2, b2_l, scsh, (float*)d_out, nullptr, nullptr, N);
}

// Round 7
// 310.415 us; speedup vs baseline: 9.6919x; 1.0746x over previous
//
#include <hip/hip_runtime.h>

#define D 128
#define EPS 1e-5f
#define SCAN_CHUNK 2048

typedef unsigned int uint;
typedef __attribute__((ext_vector_type(4))) float f32x4;
typedef __attribute__((ext_vector_type(8))) short s16x8;

// ---- bf16 pack/unpack helpers (RTNE) ---------------------------------------
__device__ __forceinline__ uint pack_bf16(float a, float b)
{
    uint ua = __float_as_uint(a);
    uint ub = __float_as_uint(b);
    ua += 0x7FFFu + ((ua >> 16) & 1u);
    ub += 0x7FFFu + ((ub >> 16) & 1u);
    return (ua >> 16) | (ub & 0xFFFF0000u);
}
__device__ __forceinline__ float bf_lo(uint v) { return __uint_as_float(v << 16); }
__device__ __forceinline__ float bf_hi(uint v) { return __uint_as_float(v & 0xFFFF0000u); }

// ---- prep: x -> xb (bf16) AND wb1/wb2 (bf16, MFMA B-fragment order) --------
__global__ void prep_kernel(const float* __restrict__ x, uint* __restrict__ xb, int ncvt,
                            const float* __restrict__ w1l, const float* __restrict__ w1r,
                            const float* __restrict__ w2l, const float* __restrict__ w2r,
                            uint* __restrict__ wb1, uint* __restrict__ wb2)
{
    int idx = blockIdx.x * 256 + threadIdx.x;
    if (idx < ncvt) {
        float4 v = ((const float4*)x)[idx];
        uint2 o;
        o.x = pack_bf16(v.x, v.y);
        o.y = pack_bf16(v.z, v.w);
        ((uint2*)xb)[idx] = o;
    } else {
        int r = idx - ncvt;          // 0..8191
        if (r < 8192) {
            int layer = r >> 12;
            int rem = r & 4095;
            int lane = rem & 63;
            int knt = rem >> 6;
            int kstep = knt >> 3, nt = knt & 7;
            int nn = nt * 16 + (lane & 15);
            int kbase = kstep * 32 + (lane >> 4) * 8;
            const float* wl = layer ? w2l : w1l;
            const float* wr = layer ? w2r : w1r;
            uint* wb = layer ? wb2 : wb1;
            float v[8];
#pragma unroll
            for (int j = 0; j < 8; j++) {
                int k = kbase + j;
                v[j] = (k < D) ? wl[nn * D + k] : wr[nn * D + (k - D)];
            }
            uint4 o;
            o.x = pack_bf16(v[0], v[1]);
            o.y = pack_bf16(v[2], v[3]);
            o.z = pack_bf16(v[4], v[5]);
            o.w = pack_bf16(v[6], v[7]);
            ((uint4*)wb)[(kstep * 8 + nt) * 64 + lane] = o;
        }
    }
}

// ---- CSR build --------------------------------------------------------------
__global__ void hist_kernel(const int* __restrict__ dst, int* __restrict__ deg, int E)
{
    int e = blockIdx.x * 256 + threadIdx.x;
    if (e < E) atomicAdd(&deg[dst[e]], 1);
}

__global__ __launch_bounds__(256) void scanA_kernel(const int* __restrict__ deg,
                                                    int* __restrict__ bsum, int n)
{
    __shared__ int red[256];
    int base = blockIdx.x * SCAN_CHUNK;
    int s = 0;
    for (int i = threadIdx.x; i < SCAN_CHUNK; i += 256) {
        int idx = base + i;
        if (idx < n) s += deg[idx];
    }
    red[threadIdx.x] = s;
    __syncthreads();
    for (int off = 128; off > 0; off >>= 1) {
        if (threadIdx.x < off) red[threadIdx.x] += red[threadIdx.x + off];
        __syncthreads();
    }
    if (threadIdx.x == 0) bsum[blockIdx.x] = red[0];
}

__global__ void scanB_kernel(int* __restrict__ bsum, int nb)
{
    int t = threadIdx.x;
    int v = (t < nb) ? bsum[t] : 0;
    for (int off = 1; off < 64; off <<= 1) {
        int u = __shfl_up(v, off);
        if (t >= off) v += u;
    }
    int ex = __shfl_up(v, 1);
    if (t == 0) ex = 0;
    if (t < nb) bsum[t] = ex;
}

__global__ __launch_bounds__(256) void scanC_kernel(const int* __restrict__ deg,
                                                    const int* __restrict__ bsum,
                                                    int* __restrict__ rowptr,
                                                    int* __restrict__ cursor, int n, int E)
{
    __shared__ int tsum[256];
    int t = threadIdx.x;
    int tb = blockIdx.x * SCAN_CHUNK + t * 8;
    int v[8];
    int s = 0;
#pragma unroll
    for (int k = 0; k < 8; k++) {
        int idx = tb + k;
        v[k] = (idx < n) ? deg[idx] : 0;
        s += v[k];
    }
    tsum[t] = s;
    __syncthreads();
    for (int off = 1; off < 256; off <<= 1) {
        int u = (t >= off) ? tsum[t - off] : 0;
        __syncthreads();
        tsum[t] += u;
        __syncthreads();
    }
    int run = bsum[blockIdx.x] + tsum[t] - s;
#pragma unroll
    for (int k = 0; k < 8; k++) {
        int idx = tb + k;
        if (idx < n) { rowptr[idx] = run; cursor[idx] = run; run += v[k]; }
    }
    if (blockIdx.x == 0 && t == 0) rowptr[n] = E;
}

__global__ void fill_kernel(const int* __restrict__ src, const int* __restrict__ dst,
                            int* __restrict__ cursor, int* __restrict__ col, int E)
{
    int e = blockIdx.x * 256 + threadIdx.x;
    if (e < E) {
        int p = atomicAdd(&cursor[dst[e]], 1);
        col[p] = src[e];
    }
}

// ---- gather aggregation, uint4 4-row gathers, optional inline BN+ReLU ------
template<bool BN>
__global__ __launch_bounds__(256) void agg_kernel(const int* __restrict__ rowptr,
                                                  const int* __restrict__ col,
                                                  const uint* __restrict__ featb,
                                                  const float* __restrict__ scsh,
                                                  uint* __restrict__ aggb, int n)
{
    int node = blockIdx.x * 4 + (threadIdx.x >> 6);
    if (node >= n) return;
    int lane = threadIdx.x & 63;
    int sub = lane >> 4, l16 = lane & 15;
    int r0 = rowptr[node], r1 = rowptr[node + 1];
    uint4* out4 = (uint4*)aggb;
    if (r0 == r1) {
        if (lane < 16) out4[(size_t)node * 16 + l16] = make_uint4(0, 0, 0, 0);
        return;
    }
    float sc[8], sh[8];
    if (BN) {
        float4 s0 = ((const float4*)scsh)[l16 * 2];
        float4 s1 = ((const float4*)scsh)[l16 * 2 + 1];
        float4 t0 = ((const float4*)scsh)[32 + l16 * 2];
        float4 t1 = ((const float4*)scsh)[32 + l16 * 2 + 1];
        sc[0] = s0.x; sc[1] = s0.y; sc[2] = s0.z; sc[3] = s0.w;
        sc[4] = s1.x; sc[5] = s1.y; sc[6] = s1.z; sc[7] = s1.w;
        sh[0] = t0.x; sh[1] = t0.y; sh[2] = t0.z; sh[3] = t0.w;
        sh[4] = t1.x; sh[5] = t1.y; sh[6] = t1.z; sh[7] = t1.w;
    }
    float acc[8] = {0.f, 0.f, 0.f, 0.f, 0.f, 0.f, 0.f, 0.f};
    const uint4* fb = (const uint4*)featb;

    auto accum = [&](uint4 v) {
        float e[8] = {bf_lo(v.x), bf_hi(v.x), bf_lo(v.y), bf_hi(v.y),
                      bf_lo(v.z), bf_hi(v.z), bf_lo(v.w), bf_hi(v.w)};
#pragma unroll
        for (int j = 0; j < 8; j++) {
            float t = e[j];
            if (BN) t = fmaxf(t * sc[j] + sh[j], 0.f);
            acc[j] += t;
        }
    };

    int i = r0;
    for (; i + 16 <= r1; i += 16) {
        int c0 = col[i + sub], c1 = col[i + 4 + sub];
        int c2 = col[i + 8 + sub], c3 = col[i + 12 + sub];
        uint4 v0 = fb[(size_t)c0 * 16 + l16];
        uint4 v1 = fb[(size_t)c1 * 16 + l16];
        uint4 v2 = fb[(size_t)c2 * 16 + l16];
        uint4 v3 = fb[(size_t)c3 * 16 + l16];
        accum(v0); accum(v1); accum(v2); accum(v3);
    }
    for (; i < r1; i += 4) {
        int idx = i + sub;
        if (idx < r1) {
            uint4 v = fb[(size_t)col[idx] * 16 + l16];
            accum(v);
        }
    }
#pragma unroll
    for (int j = 0; j < 8; j++) {
        acc[j] += __shfl_down(acc[j], 32);
        acc[j] += __shfl_down(acc[j], 16);
    }
    if (lane < 16) {
        float inv = 1.0f / (float)(r1 - r0);
        uint4 o;
        o.x = pack_bf16(acc[0] * inv, acc[1] * inv);
        o.y = pack_bf16(acc[2] * inv, acc[3] * inv);
        o.z = pack_bf16(acc[4] * inv, acc[5] * inv);
        o.w = pack_bf16(acc[6] * inv, acc[7] * inv);
        out4[(size_t)node * 16 + l16] = o;
    }
}

// ---- MFMA conv --------------------------------------------------------------
// FUSE1: write bf16 hb + per-block BN-stat partials (NO global atomics).
// BNP2: apply BN+ReLU inline to the p2 (root) A-fragments; write fp32 out.
#define TSTRIDE 132
template<bool FUSE1, bool BNP2>
__global__ __launch_bounds__(256) void conv_kernel(
    const uint* __restrict__ p1b, const uint* __restrict__ p2b,
    const uint* __restrict__ wb, const float* __restrict__ bias,
    const float* __restrict__ scsh, float* __restrict__ outf,
    uint* __restrict__ outb, float* __restrict__ pstats, int n)
{
    extern __shared__ float smem[];   // FUSE1: tile[64][TSTRIDE]; BNP2: scs[256]
    float* tile = smem;
    float* scs = smem;
    int w = threadIdx.x >> 6, lane = threadIdx.x & 63;
    int quad = lane >> 4, l15 = lane & 15;
    int nb = blockIdx.x * 64;

    if (BNP2) {
        scs[threadIdx.x] = scsh[threadIdx.x];
        __syncthreads();
    }

    const uint4* p1 = (const uint4*)p1b;
    const uint4* p2 = (const uint4*)p2b;
    const uint4* wv = (const uint4*)wb;

    uint4 B[8][2];
    int nt0 = w * 2;
#pragma unroll
    for (int ks = 0; ks < 8; ks++) {
#pragma unroll
        for (int t = 0; t < 2; t++)
            B[ks][t] = wv[(ks * 8 + nt0 + t) * 64 + lane];
    }

    float bv0 = bias[nt0 * 16 + l15];
    float bv1 = bias[nt0 * 16 + 16 + l15];

    for (int rt = 0; rt < 4; rt++) {
        int node = nb + rt * 16 + l15;
        int nc = min(node, n - 1);
        uint4 A[8];
#pragma unroll
        for (int ks = 0; ks < 4; ks++) A[ks] = p1[(size_t)nc * 16 + ks * 4 + quad];
#pragma unroll
        for (int ks = 0; ks < 4; ks++) A[ks + 4] = p2[(size_t)nc * 16 + ks * 4 + quad];

        if (BNP2) {
#pragma unroll
            for (int ks = 4; ks < 8; ks++) {
                int c0 = (ks - 4) * 32 + quad * 8;
                uint4 u = A[ks];
                float e[8] = {bf_lo(u.x), bf_hi(u.x), bf_lo(u.y), bf_hi(u.y),
                              bf_lo(u.z), bf_hi(u.z), bf_lo(u.w), bf_hi(u.w)};
#pragma unroll
                for (int j = 0; j < 8; j++)
                    e[j] = fmaxf(e[j] * scs[c0 + j] + scs[128 + c0 + j], 0.f);
                u.x = pack_bf16(e[0], e[1]);
                u.y = pack_bf16(e[2], e[3]);
                u.z = pack_bf16(e[4], e[5]);
                u.w = pack_bf16(e[6], e[7]);
                A[ks] = u;
            }
        }

        f32x4 acc0 = {bv0, bv0, bv0, bv0};
        f32x4 acc1 = {bv1, bv1, bv1, bv1};
#pragma unroll
        for (int ks = 0; ks < 8; ks++) {
            s16x8 a = *(s16x8*)&A[ks];
            acc0 = __builtin_amdgcn_mfma_f32_16x16x32_bf16(a, *(s16x8*)&B[ks][0], acc0, 0, 0, 0);
            acc1 = __builtin_amdgcn_mfma_f32_16x16x32_bf16(a, *(s16x8*)&B[ks][1], acc1, 0, 0, 0);
        }
        // C/D: col = lane&15, row = quad*4 + reg
        int row0 = nb + rt * 16 + quad * 4;
        int colbase = nt0 * 16 + l15;
        if (FUSE1) {
            int rloc0 = rt * 16 + quad * 4;
#pragma unroll
            for (int reg = 0; reg < 4; reg++) {
                bool ok = (row0 + reg) < n;
                tile[(rloc0 + reg) * TSTRIDE + colbase]      = ok ? acc0[reg] : 0.f;
                tile[(rloc0 + reg) * TSTRIDE + colbase + 16] = ok ? acc1[reg] : 0.f;
            }
        } else {
#pragma unroll
            for (int reg = 0; reg < 4; reg++) {
                int row = row0 + reg;
                if (row < n) {
                    outf[(size_t)row * D + colbase] = acc0[reg];
                    outf[(size_t)row * D + colbase + 16] = acc1[reg];
                }
            }
        }
    }

    if (FUSE1) {
        __syncthreads();
        // per-block column partial sums -> pstats (coalesced, no atomics)
        int colj = threadIdx.x & 127, half = threadIdx.x >> 7;
        float s = 0.f, ss = 0.f;
        for (int r = half * 32; r < half * 32 + 32; r++) {
            float v = tile[r * TSTRIDE + colj];
            s += v;
            ss += v * v;
        }
        float* pb = pstats + (size_t)blockIdx.x * 512 + half * 256;
        pb[colj] = s;
        pb[128 + colj] = ss;
        // pack tile -> bf16 hb
        uint4* ob4 = (uint4*)outb;
#pragma unroll
        for (int q4 = 0; q4 < 4; q4++) {
            int idx = q4 * 256 + threadIdx.x;   // 0..1023
            int r = idx >> 4, q = idx & 15;
            int row = nb + r;
            if (row < n) {
                float* tr = &tile[r * TSTRIDE + q * 8];
                uint4 o;
                o.x = pack_bf16(tr[0], tr[1]);
                o.y = pack_bf16(tr[2], tr[3]);
                o.z = pack_bf16(tr[4], tr[5]);
                o.w = pack_bf16(tr[6], tr[7]);
                ob4[(size_t)row * 16 + q] = o;
            }
        }
    }
}

// ---- reduce per-block stat partials into stats[256] ------------------------
// pstats has nparts rows of 256 floats ([0..127]=sum, [128..255]=sumsq).
__global__ __launch_bounds__(256) void reduce_kernel(const float* __restrict__ pstats,
                                                     float* __restrict__ stats, int nparts)
{
    int j = threadIdx.x;
    int chunk = (nparts + gridDim.x - 1) / gridDim.x;
    int p0 = blockIdx.x * chunk;
    int p1 = min(p0 + chunk, nparts);
    float s = 0.f;
    for (int p = p0; p < p1; p++) s += pstats[(size_t)p * 256 + j];
    unsafeAtomicAdd(&stats[j], s);
}

// ---- BN scale/shift from stats ---------------------------------------------
__global__ void bnfin_kernel(const float* __restrict__ stats, const float* __restrict__ gamma,
                             const float* __restrict__ beta, float* __restrict__ scsh, float n_inv)
{
    int j = threadIdx.x;
    float mean = stats[j] * n_inv;
    float var = fmaxf(stats[128 + j] * n_inv - mean * mean, 0.f);
    float sc = gamma[j] * rsqrtf(var + EPS);
    scsh[j] = sc;
    scsh[128 + j] = beta[j] - mean * sc;
}

extern "C" void kernel_launch(void* const* d_in, const int* in_sizes, int n_in,
                              void* d_out, int out_size, void* d_ws, size_t ws_size,
                              hipStream_t stream)
{
    const float* x     = (const float*)d_in[0];
    const int*   ei    = (const int*)d_in[1];
    const float* w1_l  = (const float*)d_in[2];
    const float* b1_l  = (const float*)d_in[3];
    const float* w1_r  = (const float*)d_in[4];
    const float* w2_l  = (const float*)d_in[5];
    const float* b2_l  = (const float*)d_in[6];
    const float* w2_r  = (const float*)d_in[7];
    const float* gamma = (const float*)d_in[8];
    const float* beta  = (const float*)d_in[9];

    int N = in_sizes[0] / D;
    int E = in_sizes[1] / 2;
    const int* src = ei;
    const int* dst = ei + E;

    int cblocks = (N + 63) / 64;

    // workspace layout:
    // uints: aggb[N*64] | xb[N*64] | hb[N*64] | wb1[16384] | wb2[16384]
    // floats: stats[256] | scsh[256] | pstats[cblocks*512]
    // ints: deg[N] | rowptr[N+1] | cursor[N] | col[E] | bsum[64]
    uint*  aggb   = (uint*)d_ws;
    uint*  xb     = aggb + (size_t)N * 64;
    uint*  hb     = xb + (size_t)N * 64;
    uint*  wb1    = hb + (size_t)N * 64;
    uint*  wb2    = wb1 + 16384;
    float* stats  = (float*)(wb2 + 16384);
    float* scsh   = stats + 256;
    float* pstats = scsh + 256;
    int*   deg    = (int*)(pstats + (size_t)cblocks * 512);
    int*   rowptr = deg + N;
    int*   cursor = rowptr + N + 1;
    int*   col    = cursor + N;
    int*   bsum   = col + E;

    hipMemsetAsync(deg, 0, (size_t)N * sizeof(int), stream);
    hipMemsetAsync(stats, 0, 256 * sizeof(float), stream);

    int ncvt = N * 32;
    int pblocks = (ncvt + 8192 + 255) / 256;
    prep_kernel<<<pblocks, 256, 0, stream>>>(x, xb, ncvt, w1_l, w1_r, w2_l, w2_r, wb1, wb2);

    int eblocks = (E + 255) / 256;
    int ablocks = (N + 3) / 4;
    int nscan   = (N + SCAN_CHUNK - 1) / SCAN_CHUNK;

    // CSR build (shared by both layers)
    hist_kernel<<<eblocks, 256, 0, stream>>>(dst, deg, E);
    scanA_kernel<<<nscan, 256, 0, stream>>>(deg, bsum, N);
    scanB_kernel<<<1, 64, 0, stream>>>(bsum, nscan);
    scanC_kernel<<<nscan, 256, 0, stream>>>(deg, bsum, rowptr, cursor, N, E);
    fill_kernel<<<eblocks, 256, 0, stream>>>(src, dst, cursor, col, E);

    // layer 1: agg + conv (conv writes bf16 hb and per-block BN-stat partials)
    agg_kernel<false><<<ablocks, 256, 0, stream>>>(rowptr, col, xb, nullptr, aggb, N);
    conv_kernel<true, false><<<cblocks, 256, 64 * TSTRIDE * 4, stream>>>(
        aggb, xb, wb1, b1_l, nullptr, nullptr, hb, pstats, N);

    // reduce partials, then BN scale/shift
    reduce_kernel<<<32, 256, 0, stream>>>(pstats, stats, cblocks * 2);
    bnfin_kernel<<<1, 128, 0, stream>>>(stats, gamma, beta, scsh, 1.0f / (float)N);

    // layer 2: agg applies BN+ReLU inline; conv applies BN+ReLU to root term
    agg_kernel<true><<<ablocks, 256, 0, stream>>>(rowptr, col, hb, scsh, aggb, N);
    conv_kernel<false, true><<<cblocks, 256, 256 * 4, stream>>>(
        aggb, hb, wb2, b2_l, scsh, (float*)d_out, nullptr, nullptr, N);
}

// Round 8
// 289.541 us; speedup vs baseline: 10.3906x; 1.0721x over previous
//
#include <hip/hip_runtime.h>

#define D 128
#define EPS 1e-5f
#define SCAN_CHUNK 2048
#define FB_EPB 8   // edges per thread in bfill (512 threads -> 4096 edges/block)

typedef unsigned int uint;
typedef __attribute__((ext_vector_type(4))) float f32x4;
typedef __attribute__((ext_vector_type(8))) short s16x8;

// ---- bf16 pack/unpack helpers (RTNE) ---------------------------------------
__device__ __forceinline__ uint pack_bf16(float a, float b)
{
    uint ua = __float_as_uint(a);
    uint ub = __float_as_uint(b);
    ua += 0x7FFFu + ((ua >> 16) & 1u);
    ub += 0x7FFFu + ((ub >> 16) & 1u);
    return (ua >> 16) | (ub & 0xFFFF0000u);
}
__device__ __forceinline__ float bf_lo(uint v) { return __uint_as_float(v << 16); }
__device__ __forceinline__ float bf_hi(uint v) { return __uint_as_float(v & 0xFFFF0000u); }

// ---- prep: x -> xb (bf16) AND wb1/wb2 (bf16, MFMA B-fragment order) --------
__global__ void prep_kernel(const float* __restrict__ x, uint* __restrict__ xb, int ncvt,
                            const float* __restrict__ w1l, const float* __restrict__ w1r,
                            const float* __restrict__ w2l, const float* __restrict__ w2r,
                            uint* __restrict__ wb1, uint* __restrict__ wb2)
{
    int idx = blockIdx.x * 256 + threadIdx.x;
    if (idx < ncvt) {
        float4 v = ((const float4*)x)[idx];
        uint2 o;
        o.x = pack_bf16(v.x, v.y);
        o.y = pack_bf16(v.z, v.w);
        ((uint2*)xb)[idx] = o;
    } else {
        int r = idx - ncvt;          // 0..8191
        if (r < 8192) {
            int layer = r >> 12;
            int rem = r & 4095;
            int lane = rem & 63;
            int knt = rem >> 6;
            int kstep = knt >> 3, nt = knt & 7;
            int nn = nt * 16 + (lane & 15);
            int kbase = kstep * 32 + (lane >> 4) * 8;
            const float* wl = layer ? w2l : w1l;
            const float* wr = layer ? w2r : w1r;
            uint* wb = layer ? wb2 : wb1;
            float v[8];
#pragma unroll
            for (int j = 0; j < 8; j++) {
                int k = kbase + j;
                v[j] = (k < D) ? wl[nn * D + k] : wr[nn * D + (k - D)];
            }
            uint4 o;
            o.x = pack_bf16(v[0], v[1]);
            o.y = pack_bf16(v[2], v[3]);
            o.z = pack_bf16(v[4], v[5]);
            o.w = pack_bf16(v[6], v[7]);
            ((uint4*)wb)[(kstep * 8 + nt) * 64 + lane] = o;
        }
    }
}

// ---- CSR build --------------------------------------------------------------
__global__ void hist_kernel(const int* __restrict__ dst, int* __restrict__ deg, int E)
{
    int e = blockIdx.x * 256 + threadIdx.x;
    if (e < E) atomicAdd(&deg[dst[e]], 1);
}

__global__ __launch_bounds__(256) void scanA_kernel(const int* __restrict__ deg,
                                                    int* __restrict__ bsum, int n)
{
    __shared__ int red[256];
    int base = blockIdx.x * SCAN_CHUNK;
    int s = 0;
    for (int i = threadIdx.x; i < SCAN_CHUNK; i += 256) {
        int idx = base + i;
        if (idx < n) s += deg[idx];
    }
    red[threadIdx.x] = s;
    __syncthreads();
    for (int off = 128; off > 0; off >>= 1) {
        if (threadIdx.x < off) red[threadIdx.x] += red[threadIdx.x + off];
        __syncthreads();
    }
    if (threadIdx.x == 0) bsum[blockIdx.x] = red[0];
}

__global__ void scanB_kernel(int* __restrict__ bsum, int nb)
{
    int t = threadIdx.x;
    int v = (t < nb) ? bsum[t] : 0;
    for (int off = 1; off < 64; off <<= 1) {
        int u = __shfl_up(v, off);
        if (t >= off) v += u;
    }
    int ex = __shfl_up(v, 1);
    if (t == 0) ex = 0;
    if (t < nb) bsum[t] = ex;
}

// writes rowptr; also seeds line-padded bucket cursors bcur[b*16] = rowptr[b*512]
__global__ __launch_bounds__(256) void scanC_kernel(const int* __restrict__ deg,
                                                    const int* __restrict__ bsum,
                                                    int* __restrict__ rowptr,
                                                    int* __restrict__ bcur, int n, int E)
{
    __shared__ int tsum[256];
    int t = threadIdx.x;
    int tb = blockIdx.x * SCAN_CHUNK + t * 8;
    int v[8];
    int s = 0;
#pragma unroll
    for (int k = 0; k < 8; k++) {
        int idx = tb + k;
        v[k] = (idx < n) ? deg[idx] : 0;
        s += v[k];
    }
    tsum[t] = s;
    __syncthreads();
    for (int off = 1; off < 256; off <<= 1) {
        int u = (t >= off) ? tsum[t - off] : 0;
        __syncthreads();
        tsum[t] += u;
        __syncthreads();
    }
    int run = bsum[blockIdx.x] + tsum[t] - s;
#pragma unroll
    for (int k = 0; k < 8; k++) {
        int idx = tb + k;
        if (idx < n) {
            rowptr[idx] = run;
            if ((idx & 511) == 0) bcur[(idx >> 9) * 16] = run;
            run += v[k];
        }
    }
    if (blockIdx.x == 0 && t == 0) rowptr[n] = E;
}

// ---- bucketed fill phase 1: edges -> ebuf, bucket-contiguous ---------------
// bucket = dst>>9 (512 nodes). Per-block LDS histogram; one line-padded global
// atomic per (block,bucket); writes are ~340B contiguous runs.
__global__ __launch_bounds__(512) void bfill_kernel(const int* __restrict__ src,
                                                    const int* __restrict__ dst,
                                                    int* __restrict__ bcur,
                                                    uint2* __restrict__ ebuf,
                                                    int E, int nbuck)
{
    __shared__ int cnt[128], base[128];
    int t = threadIdx.x;
    if (t < 128) cnt[t] = 0;
    __syncthreads();
    int e0 = blockIdx.x * (512 * FB_EPB);
    int s[FB_EPB], d[FB_EPB], loc[FB_EPB];
#pragma unroll
    for (int k = 0; k < FB_EPB; k++) {
        int e = e0 + k * 512 + t;
        if (e < E) {
            s[k] = src[e];
            d[k] = dst[e];
            loc[k] = atomicAdd(&cnt[d[k] >> 9], 1);
        }
    }
    __syncthreads();
    if (t < nbuck) base[t] = atomicAdd(&bcur[t * 16], cnt[t]);
    __syncthreads();
#pragma unroll
    for (int k = 0; k < FB_EPB; k++) {
        int e = e0 + k * 512 + t;
        if (e < E) {
            int b = d[k] >> 9;
            ebuf[base[b] + loc[k]] = make_uint2((uint)s[k], (uint)d[k]);
        }
    }
}

// ---- bucketed fill phase 2: ebuf -> col via LDS cursors (one block/bucket) -
__global__ __launch_bounds__(512) void pfill_kernel(const int* __restrict__ rowptr,
                                                    const uint2* __restrict__ ebuf,
                                                    int* __restrict__ col, int n)
{
    __shared__ int lcur[512];
    int t = threadIdx.x;
    int nb = blockIdx.x << 9;
    int ncnt = min(512, n - nb);
    if (t < ncnt) lcur[t] = rowptr[nb + t];
    __syncthreads();
    int e0 = rowptr[nb];
    int e1 = rowptr[min(nb + 512, n)];
    for (int i = e0 + t; i < e1; i += 512) {
        uint2 ed = ebuf[i];
        int p = atomicAdd(&lcur[(int)ed.y - nb], 1);
        col[p] = (int)ed.x;
    }
}

// ---- gather aggregation, uint4 4-row gathers, optional inline BN+ReLU ------
template<bool BN>
__global__ __launch_bounds__(256) void agg_kernel(const int* __restrict__ rowptr,
                                                  const int* __restrict__ col,
                                                  const uint* __restrict__ featb,
                                                  const float* __restrict__ scsh,
                                                  uint* __restrict__ aggb, int n)
{
    int node = blockIdx.x * 4 + (threadIdx.x >> 6);
    if (node >= n) return;
    int lane = threadIdx.x & 63;
    int sub = lane >> 4, l16 = lane & 15;
    int r0 = rowptr[node], r1 = rowptr[node + 1];
    uint4* out4 = (uint4*)aggb;
    if (r0 == r1) {
        if (lane < 16) out4[(size_t)node * 16 + l16] = make_uint4(0, 0, 0, 0);
        return;
    }
    float sc[8], sh[8];
    if (BN) {
        float4 s0 = ((const float4*)scsh)[l16 * 2];
        float4 s1 = ((const float4*)scsh)[l16 * 2 + 1];
        float4 t0 = ((const float4*)scsh)[32 + l16 * 2];
        float4 t1 = ((const float4*)scsh)[32 + l16 * 2 + 1];
        sc[0] = s0.x; sc[1] = s0.y; sc[2] = s0.z; sc[3] = s0.w;
        sc[4] = s1.x; sc[5] = s1.y; sc[6] = s1.z; sc[7] = s1.w;
        sh[0] = t0.x; sh[1] = t0.y; sh[2] = t0.z; sh[3] = t0.w;
        sh[4] = t1.x; sh[5] = t1.y; sh[6] = t1.z; sh[7] = t1.w;
    }
    float acc[8] = {0.f, 0.f, 0.f, 0.f, 0.f, 0.f, 0.f, 0.f};
    const uint4* fb = (const uint4*)featb;

    auto accum = [&](uint4 v) {
        float e[8] = {bf_lo(v.x), bf_hi(v.x), bf_lo(v.y), bf_hi(v.y),
                      bf_lo(v.z), bf_hi(v.z), bf_lo(v.w), bf_hi(v.w)};
#pragma unroll
        for (int j = 0; j < 8; j++) {
            float t = e[j];
            if (BN) t = fmaxf(t * sc[j] + sh[j], 0.f);
            acc[j] += t;
        }
    };

    int i = r0;
    for (; i + 16 <= r1; i += 16) {
        int c0 = col[i + sub], c1 = col[i + 4 + sub];
        int c2 = col[i + 8 + sub], c3 = col[i + 12 + sub];
        uint4 v0 = fb[(size_t)c0 * 16 + l16];
        uint4 v1 = fb[(size_t)c1 * 16 + l16];
        uint4 v2 = fb[(size_t)c2 * 16 + l16];
        uint4 v3 = fb[(size_t)c3 * 16 + l16];
        accum(v0); accum(v1); accum(v2); accum(v3);
    }
    for (; i < r1; i += 4) {
        int idx = i + sub;
        if (idx < r1) {
            uint4 v = fb[(size_t)col[idx] * 16 + l16];
            accum(v);
        }
    }
#pragma unroll
    for (int j = 0; j < 8; j++) {
        acc[j] += __shfl_down(acc[j], 32);
        acc[j] += __shfl_down(acc[j], 16);
    }
    if (lane < 16) {
        float inv = 1.0f / (float)(r1 - r0);
        uint4 o;
        o.x = pack_bf16(acc[0] * inv, acc[1] * inv);
        o.y = pack_bf16(acc[2] * inv, acc[3] * inv);
        o.z = pack_bf16(acc[4] * inv, acc[5] * inv);
        o.w = pack_bf16(acc[6] * inv, acc[7] * inv);
        out4[(size_t)node * 16 + l16] = o;
    }
}

// ---- MFMA conv --------------------------------------------------------------
// FUSE1: write bf16 hb + per-block BN-stat partials (NO global atomics).
// BNP2: apply BN+ReLU inline to the p2 (root) A-fragments; write fp32 out.
#define TSTRIDE 132
template<bool FUSE1, bool BNP2>
__global__ __launch_bounds__(256) void conv_kernel(
    const uint* __restrict__ p1b, const uint* __restrict__ p2b,
    const uint* __restrict__ wb, const float* __restrict__ bias,
    const float* __restrict__ scsh, float* __restrict__ outf,
    uint* __restrict__ outb, float* __restrict__ pstats, int n)
{
    extern __shared__ float smem[];   // FUSE1: tile[64][TSTRIDE]; BNP2: scs[256]
    float* tile = smem;
    float* scs = smem;
    int w = threadIdx.x >> 6, lane = threadIdx.x & 63;
    int quad = lane >> 4, l15 = lane & 15;
    int nb = blockIdx.x * 64;

    if (BNP2) {
        scs[threadIdx.x] = scsh[threadIdx.x];
        __syncthreads();
    }

    const uint4* p1 = (const uint4*)p1b;
    const uint4* p2 = (const uint4*)p2b;
    const uint4* wv = (const uint4*)wb;

    uint4 B[8][2];
    int nt0 = w * 2;
#pragma unroll
    for (int ks = 0; ks < 8; ks++) {
#pragma unroll
        for (int t = 0; t < 2; t++)
            B[ks][t] = wv[(ks * 8 + nt0 + t) * 64 + lane];
    }

    float bv0 = bias[nt0 * 16 + l15];
    float bv1 = bias[nt0 * 16 + 16 + l15];

    for (int rt = 0; rt < 4; rt++) {
        int node = nb + rt * 16 + l15;
        int nc = min(node, n - 1);
        uint4 A[8];
#pragma unroll
        for (int ks = 0; ks < 4; ks++) A[ks] = p1[(size_t)nc * 16 + ks * 4 + quad];
#pragma unroll
        for (int ks = 0; ks < 4; ks++) A[ks + 4] = p2[(size_t)nc * 16 + ks * 4 + quad];

        if (BNP2) {
#pragma unroll
            for (int ks = 4; ks < 8; ks++) {
                int c0 = (ks - 4) * 32 + quad * 8;
                uint4 u = A[ks];
                float e[8] = {bf_lo(u.x), bf_hi(u.x), bf_lo(u.y), bf_hi(u.y),
                              bf_lo(u.z), bf_hi(u.z), bf_lo(u.w), bf_hi(u.w)};
#pragma unroll
                for (int j = 0; j < 8; j++)
                    e[j] = fmaxf(e[j] * scs[c0 + j] + scs[128 + c0 + j], 0.f);
                u.x = pack_bf16(e[0], e[1]);
                u.y = pack_bf16(e[2], e[3]);
                u.z = pack_bf16(e[4], e[5]);
                u.w = pack_bf16(e[6], e[7]);
                A[ks] = u;
            }
        }

        f32x4 acc0 = {bv0, bv0, bv0, bv0};
        f32x4 acc1 = {bv1, bv1, bv1, bv1};
#pragma unroll
        for (int ks = 0; ks < 8; ks++) {
            s16x8 a = *(s16x8*)&A[ks];
            acc0 = __builtin_amdgcn_mfma_f32_16x16x32_bf16(a, *(s16x8*)&B[ks][0], acc0, 0, 0, 0);
            acc1 = __builtin_amdgcn_mfma_f32_16x16x32_bf16(a, *(s16x8*)&B[ks][1], acc1, 0, 0, 0);
        }
        // C/D: col = lane&15, row = quad*4 + reg
        int row0 = nb + rt * 16 + quad * 4;
        int colbase = nt0 * 16 + l15;
        if (FUSE1) {
            int rloc0 = rt * 16 + quad * 4;
#pragma unroll
            for (int reg = 0; reg < 4; reg++) {
                bool ok = (row0 + reg) < n;
                tile[(rloc0 + reg) * TSTRIDE + colbase]      = ok ? acc0[reg] : 0.f;
                tile[(rloc0 + reg) * TSTRIDE + colbase + 16] = ok ? acc1[reg] : 0.f;
            }
        } else {
#pragma unroll
            for (int reg = 0; reg < 4; reg++) {
                int row = row0 + reg;
                if (row < n) {
                    outf[(size_t)row * D + colbase] = acc0[reg];
                    outf[(size_t)row * D + colbase + 16] = acc1[reg];
                }
            }
        }
    }

    if (FUSE1) {
        __syncthreads();
        // per-block column partial sums -> pstats (coalesced, no atomics)
        int colj = threadIdx.x & 127, half = threadIdx.x >> 7;
        float s = 0.f, ss = 0.f;
        for (int r = half * 32; r < half * 32 + 32; r++) {
            float v = tile[r * TSTRIDE + colj];
            s += v;
            ss += v * v;
        }
        float* pb = pstats + (size_t)blockIdx.x * 512 + half * 256;
        pb[colj] = s;
        pb[128 + colj] = ss;
        // pack tile -> bf16 hb
        uint4* ob4 = (uint4*)outb;
#pragma unroll
        for (int q4 = 0; q4 < 4; q4++) {
            int idx = q4 * 256 + threadIdx.x;   // 0..1023
            int r = idx >> 4, q = idx & 15;
            int row = nb + r;
            if (row < n) {
                float* tr = &tile[r * TSTRIDE + q * 8];
                uint4 o;
                o.x = pack_bf16(tr[0], tr[1]);
                o.y = pack_bf16(tr[2], tr[3]);
                o.z = pack_bf16(tr[4], tr[5]);
                o.w = pack_bf16(tr[6], tr[7]);
                ob4[(size_t)row * 16 + q] = o;
            }
        }
    }
}

// ---- reduce per-block stat partials into stats[256] ------------------------
__global__ __launch_bounds__(256) void reduce_kernel(const float* __restrict__ pstats,
                                                     float* __restrict__ stats, int nparts)
{
    int j = threadIdx.x;
    int chunk = (nparts + gridDim.x - 1) / gridDim.x;
    int p0 = blockIdx.x * chunk;
    int p1 = min(p0 + chunk, nparts);
    float s = 0.f;
    for (int p = p0; p < p1; p++) s += pstats[(size_t)p * 256 + j];
    unsafeAtomicAdd(&stats[j], s);
}

// ---- BN scale/shift from stats ---------------------------------------------
__global__ void bnfin_kernel(const float* __restrict__ stats, const float* __restrict__ gamma,
                             const float* __restrict__ beta, float* __restrict__ scsh, float n_inv)
{
    int j = threadIdx.x;
    float mean = stats[j] * n_inv;
    float var = fmaxf(stats[128 + j] * n_inv - mean * mean, 0.f);
    float sc = gamma[j] * rsqrtf(var + EPS);
    scsh[j] = sc;
    scsh[128 + j] = beta[j] - mean * sc;
}

extern "C" void kernel_launch(void* const* d_in, const int* in_sizes, int n_in,
                              void* d_out, int out_size, void* d_ws, size_t ws_size,
                              hipStream_t stream)
{
    const float* x     = (const float*)d_in[0];
    const int*   ei    = (const int*)d_in[1];
    const float* w1_l  = (const float*)d_in[2];
    const float* b1_l  = (const float*)d_in[3];
    const float* w1_r  = (const float*)d_in[4];
    const float* w2_l  = (const float*)d_in[5];
    const float* b2_l  = (const float*)d_in[6];
    const float* w2_r  = (const float*)d_in[7];
    const float* gamma = (const float*)d_in[8];
    const float* beta  = (const float*)d_in[9];

    int N = in_sizes[0] / D;
    int E = in_sizes[1] / 2;
    const int* src = ei;
    const int* dst = ei + E;

    int cblocks = (N + 63) / 64;
    int nbuck   = (N + 511) >> 9;

    // workspace layout:
    // uints: aggb[N*64] | xb[N*64] | hb[N*64] | wb1[16384] | wb2[16384]
    // uint2: ebuf[E]
    // floats: stats[256] | scsh[256] | pstats[cblocks*512]
    // ints: deg[N] | rowptr[N+1] | col[E] | bsum[64] | bcur[128*16]
    uint*  aggb   = (uint*)d_ws;
    uint*  xb     = aggb + (size_t)N * 64;
    uint*  hb     = xb + (size_t)N * 64;
    uint*  wb1    = hb + (size_t)N * 64;
    uint*  wb2    = wb1 + 16384;
    uint2* ebuf   = (uint2*)(wb2 + 16384);
    float* stats  = (float*)(ebuf + E);
    float* scsh   = stats + 256;
    float* pstats = scsh + 256;
    int*   deg    = (int*)(pstats + (size_t)cblocks * 512);
    int*   rowptr = deg + N;
    int*   col    = rowptr + N + 1;
    int*   bsum   = col + E;
    int*   bcur   = bsum + 64;

    hipMemsetAsync(deg, 0, (size_t)N * sizeof(int), stream);
    hipMemsetAsync(stats, 0, 256 * sizeof(float), stream);

    int ncvt = N * 32;
    int pblocks = (ncvt + 8192 + 255) / 256;
    prep_kernel<<<pblocks, 256, 0, stream>>>(x, xb, ncvt, w1_l, w1_r, w2_l, w2_r, wb1, wb2);

    int eblocks  = (E + 255) / 256;
    int ablocks  = (N + 3) / 4;
    int bfblocks = (E + 4095) / 4096;
    int nscan    = (N + SCAN_CHUNK - 1) / SCAN_CHUNK;

    // CSR build (shared by both layers)
    hist_kernel<<<eblocks, 256, 0, stream>>>(dst, deg, E);
    scanA_kernel<<<nscan, 256, 0, stream>>>(deg, bsum, N);
    scanB_kernel<<<1, 64, 0, stream>>>(bsum, nscan);
    scanC_kernel<<<nscan, 256, 0, stream>>>(deg, bsum, rowptr, bcur, N, E);
    bfill_kernel<<<bfblocks, 512, 0, stream>>>(src, dst, bcur, ebuf, E, nbuck);
    pfill_kernel<<<nbuck, 512, 0, stream>>>(rowptr, ebuf, col, N);

    // layer 1: agg + conv (conv writes bf16 hb and per-block BN-stat partials)
    agg_kernel<false><<<ablocks, 256, 0, stream>>>(rowptr, col, xb, nullptr, aggb, N);
    conv_kernel<true, false><<<cblocks, 256, 64 * TSTRIDE * 4, stream>>>(
        aggb, xb, wb1, b1_l, nullptr, nullptr, hb, pstats, N);

    // reduce partials, then BN scale/shift
    reduce_kernel<<<32, 256, 0, stream>>>(pstats, stats, cblocks * 2);
    bnfin_kernel<<<1, 128, 0, stream>>>(stats, gamma, beta, scsh, 1.0f / (float)N);

    // layer 2: agg applies BN+ReLU inline; conv applies BN+ReLU to root term
    agg_kernel<true><<<ablocks, 256, 0, stream>>>(rowptr, col, hb, scsh, aggb, N);
    conv_kernel<false, true><<<cblocks, 256, 256 * 4, stream>>>(
        aggb, hb, wb2, b2_l, scsh, (float*)d_out, nullptr, nullptr, N);
}